// Round 1
// baseline (163.060 us; speedup 1.0000x reference)
//
#include <hip/hip_runtime.h>
#include <stdint.h>

// Problem constants
#define B_  2
#define S_  2048
#define D_  1024
#define H_  16
#define DK_ 64
#define M_  (B_*S_)   // 4096 rows for the projection GEMMs

typedef unsigned short u16;
typedef __attribute__((ext_vector_type(8))) __bf16 bf16x8;
typedef __attribute__((ext_vector_type(4))) float f32x4;
typedef __attribute__((ext_vector_type(4))) short short4v;
typedef __attribute__((ext_vector_type(8))) short short8v;

// f32 -> bf16 round-to-nearest-even
static __device__ __forceinline__ u16 f2bf(float f) {
    union { float f; uint32_t u; } v; v.f = f;
    uint32_t r = (v.u + 0x7fffu + ((v.u >> 16) & 1u)) >> 16;
    return (u16)r;
}

// async global->LDS, 16B per lane. LDS dest = wave-uniform base + lane*16.
#define GLOAD16(gp, lp) \
    __builtin_amdgcn_global_load_lds((const __attribute__((address_space(1))) void*)(gp), \
                                     (__attribute__((address_space(3))) void*)(lp), 16, 0, 0)

// Universal LDS 16B-slot swizzle: phys = lin ^ ((lin>>3)&7).
// Involution (bits >=3 unchanged). Gives 2-way-or-free bank conflicts for all
// our row-major tile reads (64B and 128B rows) and stays global_load_lds
// compatible via pre-swizzled global source addressing.
static __device__ __forceinline__ int swz(int lin) { return lin ^ ((lin >> 3) & 7); }

// ---------------------------------------------------------------- cast kernel
__global__ void cast_kernel(const float* __restrict__ in, u16* __restrict__ out, int n) {
    int idx = blockIdx.x * blockDim.x + threadIdx.x;
    int stride = gridDim.x * blockDim.x;
    for (int i = idx * 8; i < n; i += stride * 8) {
        float4 a = *(const float4*)(in + i);
        float4 b = *(const float4*)(in + i + 4);
        short8v r;
        r[0] = (short)f2bf(a.x); r[1] = (short)f2bf(a.y);
        r[2] = (short)f2bf(a.z); r[3] = (short)f2bf(a.w);
        r[4] = (short)f2bf(b.x); r[5] = (short)f2bf(b.y);
        r[6] = (short)f2bf(b.z); r[7] = (short)f2bf(b.w);
        *(short8v*)(void*)(out + i) = r;
    }
}

// ------------------------------------------------- 128x128 GEMM tile (B^T form)
// C[m][n] = sum_k X[m][k] * W[n][k], X: M x 1024, W: 1024 x 1024, bf16.
// BK=32, 4 waves (2x2), per-wave 64x64, 16 MFMA 16x16x32 per K-step.
__device__ __forceinline__ void gemm128_compute(
        const u16* __restrict__ X, const u16* __restrict__ W,
        int m0, int n0, u16* As, u16* Bs, f32x4 acc[4][4]) {
    const int tid = threadIdx.x, lane = tid & 63, w = tid >> 6;
    const int wm = w >> 1, wn = w & 1;
#pragma unroll 1
    for (int kt = 0; kt < 32; ++kt) {
        // stage A/B tiles: 512 slots each, pre-swizzled source
#pragma unroll
        for (int r = 0; r < 2; ++r) {
            int s = tid + (r << 8);
            int lin = s ^ ((s >> 3) & 7);       // inverse swizzle (involution)
            int row = lin >> 2, ch = lin & 3;   // 64B rows: 4 chunks of 16B
            GLOAD16(X + (size_t)(m0 + row) * 1024 + (kt << 5) + (ch << 3),
                    (char*)As + ((r << 8) + (w << 6)) * 16);
            GLOAD16(W + (size_t)(n0 + row) * 1024 + (kt << 5) + (ch << 3),
                    (char*)Bs + ((r << 8) + (w << 6)) * 16);
        }
        asm volatile("s_waitcnt vmcnt(0)" ::: "memory");
        __syncthreads();
        bf16x8 a[4], b[4];
#pragma unroll
        for (int f = 0; f < 4; ++f) {
            int rowa = wm * 64 + f * 16 + (lane & 15);
            int pha = swz(rowa * 4 + (lane >> 4));
            a[f] = *(const bf16x8*)((const char*)As + pha * 16);
            int rowb = wn * 64 + f * 16 + (lane & 15);
            int phb = swz(rowb * 4 + (lane >> 4));
            b[f] = *(const bf16x8*)((const char*)Bs + phb * 16);
        }
#pragma unroll
        for (int fm = 0; fm < 4; ++fm)
#pragma unroll
            for (int fn = 0; fn < 4; ++fn)
                acc[fm][fn] = __builtin_amdgcn_mfma_f32_16x16x32_bf16(
                    a[fm], b[fn], acc[fm][fn], 0, 0, 0);
        __syncthreads();
    }
}

// QKV projection: fused over blockIdx.y in {0,1,2}. Stores bf16 permuted to
// [B,H,S,DK]; Q is pre-scaled by 1/sqrt(DK).
__global__ __launch_bounds__(256) void qkv_proj_kernel(
        const u16* __restrict__ qX, const u16* __restrict__ kX, const u16* __restrict__ vX,
        const u16* __restrict__ Wq, const u16* __restrict__ Wk, const u16* __restrict__ Wv,
        const float* __restrict__ bq, const float* __restrict__ bk, const float* __restrict__ bv,
        u16* __restrict__ qo, u16* __restrict__ ko, u16* __restrict__ vo) {
    __shared__ __align__(16) u16 As[4096];
    __shared__ __align__(16) u16 Bs[4096];
    const int which = blockIdx.y;
    const u16* X = which == 0 ? qX : (which == 1 ? kX : vX);
    const u16* W = which == 0 ? Wq : (which == 1 ? Wk : Wv);
    const float* bias = which == 0 ? bq : (which == 1 ? bk : bv);
    u16* out = which == 0 ? qo : (which == 1 ? ko : vo);
    const float scale = which == 0 ? 0.125f : 1.0f;   // 1/sqrt(64)

    const int bid = blockIdx.x;
    const int m0 = (bid >> 3) << 7;   // 32 m-tiles
    const int n0 = (bid & 7) << 7;    // 8 n-tiles
    f32x4 acc[4][4] = {};
    gemm128_compute(X, W, m0, n0, As, Bs, acc);

    const int lane = threadIdx.x & 63, w = threadIdx.x >> 6;
    const int wm = w >> 1, wn = w & 1;
#pragma unroll
    for (int fn = 0; fn < 4; ++fn) {
        int n = n0 + wn * 64 + fn * 16 + (lane & 15);
        float bv_ = bias[n];
        int h = n >> 6, dk = n & 63;
#pragma unroll
        for (int fm = 0; fm < 4; ++fm)
#pragma unroll
            for (int j = 0; j < 4; ++j) {
                int m = m0 + wm * 64 + fm * 16 + (lane >> 4) * 4 + j;
                int b = m >> 11, s = m & 2047;
                float vly = (acc[fm][fn][j] + bv_) * scale;
                out[((size_t)(b * H_ + h) * S_ + s) * DK_ + dk] = f2bf(vly);
            }
    }
}

// Output projection: bf16 attn-out @ Wo^T + bo -> fp32 d_out
__global__ __launch_bounds__(256) void oproj_kernel(
        const u16* __restrict__ X, const u16* __restrict__ W,
        const float* __restrict__ bias, float* __restrict__ out) {
    __shared__ __align__(16) u16 As[4096];
    __shared__ __align__(16) u16 Bs[4096];
    const int bid = blockIdx.x;
    const int m0 = (bid >> 3) << 7;
    const int n0 = (bid & 7) << 7;
    f32x4 acc[4][4] = {};
    gemm128_compute(X, W, m0, n0, As, Bs, acc);

    const int lane = threadIdx.x & 63, w = threadIdx.x >> 6;
    const int wm = w >> 1, wn = w & 1;
#pragma unroll
    for (int fn = 0; fn < 4; ++fn) {
        int n = n0 + wn * 64 + fn * 16 + (lane & 15);
        float bv_ = bias[n];
#pragma unroll
        for (int fm = 0; fm < 4; ++fm)
#pragma unroll
            for (int j = 0; j < 4; ++j) {
                int m = m0 + wm * 64 + fm * 16 + (lane >> 4) * 4 + j;
                out[(size_t)m * 1024 + n] = acc[fm][fn][j] + bv_;
            }
    }
}

// ---------------------------------------------- V transpose [BH,S,DK]->[BH,DK,S]
__global__ __launch_bounds__(256) void transpose_v_kernel(
        const u16* __restrict__ vh, u16* __restrict__ Vt) {
    __shared__ u16 t[64][80];   // padded
    const int bh = blockIdx.x >> 5, st = blockIdx.x & 31;
    const int tid = threadIdx.x;
    {
        int r = tid >> 2, c0 = (tid & 3) << 4;
        const u16* src = vh + ((size_t)bh * S_ + st * 64 + r) * DK_ + c0;
        short8v v0 = *(const short8v*)(const void*)src;
        short8v v1 = *(const short8v*)(const void*)(src + 8);
#pragma unroll
        for (int i = 0; i < 8; ++i) { t[r][c0 + i] = (u16)v0[i]; t[r][c0 + 8 + i] = (u16)v1[i]; }
    }
    __syncthreads();
    {
        int dk = tid >> 2, s0 = (tid & 3) << 4;
        short8v o0, o1;
#pragma unroll
        for (int i = 0; i < 8; ++i) { o0[i] = (short)t[s0 + i][dk]; o1[i] = (short)t[s0 + 8 + i][dk]; }
        u16* dst = Vt + ((size_t)bh * DK_ + dk) * S_ + st * 64 + s0;
        *(short8v*)(void*)dst = o0;
        *(short8v*)(void*)(dst + 8) = o1;
    }
}

// ------------------------------------------------------------ flash attention
// Per block: one (b,h), 128 q-rows. 4 waves x 32 rows. KV tiles of 64.
// Swapped QK^T: St = mfma(K, Q) => lane holds St[key=(l>>4)*4+j][qrow=l&15].
// Softmax without max-subtraction (scores std ~1, rowmax < ~7 -> exp safe).
// P staged via per-wave LDS to repack into the PV A-operand layout.
__global__ __launch_bounds__(256) void attn_kernel(
        const u16* __restrict__ qh, const u16* __restrict__ kh,
        const u16* __restrict__ Vt, u16* __restrict__ ao) {
    __shared__ __align__(16) u16 Qs[128 * 64];   // 16 KB, 1024 slots
    __shared__ __align__(16) u16 Ks[64 * 64];    // 8 KB, 512 slots
    __shared__ __align__(16) u16 Vs[64 * 64];    // 8 KB, 512 slots  (Vt tile: [dk][key])
    __shared__ __align__(16) u16 Ps[4 * 32 * 64];// 16 KB, per-wave P scratch

    const int tid = threadIdx.x, lane = tid & 63, w = tid >> 6;
    const int bh = blockIdx.x >> 4, qt = blockIdx.x & 15;
    const u16* qg = qh + ((size_t)bh * S_ + qt * 128) * DK_;
    const u16* kg = kh + (size_t)bh * S_ * DK_;
    const u16* vg = Vt + (size_t)bh * DK_ * S_;

    // stage Q tile [128][64]
#pragma unroll
    for (int r = 0; r < 4; ++r) {
        int s = tid + (r << 8);
        int lin = s ^ ((s >> 3) & 7);
        int row = lin >> 3, ch = lin & 7;      // 128B rows: 8 chunks
        GLOAD16(qg + row * 64 + (ch << 3), (char*)Qs + ((r << 8) + (w << 6)) * 16);
    }
    asm volatile("s_waitcnt vmcnt(0)" ::: "memory");
    __syncthreads();

    // preload Q fragments (B-operand): qrow = w*32+fn*16+(l&15), dk chunks
    bf16x8 qf[2][2];
#pragma unroll
    for (int fn = 0; fn < 2; ++fn)
#pragma unroll
        for (int ks = 0; ks < 2; ++ks) {
            int row = w * 32 + fn * 16 + (lane & 15);
            int ph = swz(row * 8 + ks * 4 + (lane >> 4));
            qf[fn][ks] = *(const bf16x8*)((const char*)Qs + ph * 16);
        }

    f32x4 acc[2][4] = {};
    float l_run[2] = {0.f, 0.f};
    u16* Pw = Ps + w * 2048;

#pragma unroll 1
    for (int kt = 0; kt < 32; ++kt) {
        // stage K tile [64 key][64 dk] and Vt tile [64 dk][64 key]
#pragma unroll
        for (int r = 0; r < 2; ++r) {
            int s = tid + (r << 8);
            int lin = s ^ ((s >> 3) & 7);
            int row = lin >> 3, ch = lin & 7;
            GLOAD16(kg + (size_t)(kt * 64 + row) * 64 + (ch << 3),
                    (char*)Ks + ((r << 8) + (w << 6)) * 16);
            GLOAD16(vg + (size_t)row * S_ + kt * 64 + (ch << 3),
                    (char*)Vs + ((r << 8) + (w << 6)) * 16);
        }
        asm volatile("s_waitcnt vmcnt(0)" ::: "memory");
        __syncthreads();

        // St = K . Q^T  (keys 64 = 4 m-frags, qrows 32 = 2 n-frags)
        f32x4 st[4][2] = {};
#pragma unroll
        for (int ks = 0; ks < 2; ++ks) {
            bf16x8 kf[4];
#pragma unroll
            for (int fm = 0; fm < 4; ++fm) {
                int row = fm * 16 + (lane & 15);
                int ph = swz(row * 8 + ks * 4 + (lane >> 4));
                kf[fm] = *(const bf16x8*)((const char*)Ks + ph * 16);
            }
#pragma unroll
            for (int fm = 0; fm < 4; ++fm)
#pragma unroll
                for (int fn = 0; fn < 2; ++fn)
                    st[fm][fn] = __builtin_amdgcn_mfma_f32_16x16x32_bf16(
                        kf[fm], qf[fn][ks], st[fm][fn], 0, 0, 0);
        }

        // softmax numerator + P write (per-wave private LDS region, no barrier)
        float rs[2] = {0.f, 0.f};
#pragma unroll
        for (int fm = 0; fm < 4; ++fm)
#pragma unroll
            for (int fn = 0; fn < 2; ++fn) {
                float e0 = __expf(st[fm][fn][0]);
                float e1 = __expf(st[fm][fn][1]);
                float e2 = __expf(st[fm][fn][2]);
                float e3 = __expf(st[fm][fn][3]);
                rs[fn] += (e0 + e1) + (e2 + e3);
                short4v p4;
                p4[0] = (short)f2bf(e0); p4[1] = (short)f2bf(e1);
                p4[2] = (short)f2bf(e2); p4[3] = (short)f2bf(e3);
                int qrow = fn * 16 + (lane & 15);
                int g = lane >> 4;
                int slot = qrow * 8 + fm * 2 + (g >> 1);
                int ph = slot ^ (qrow & 7);
                *(short4v*)((char*)Pw + ph * 16 + (g & 1) * 8) = p4;
            }
        rs[0] += __shfl_xor(rs[0], 16); rs[0] += __shfl_xor(rs[0], 32);
        rs[1] += __shfl_xor(rs[1], 16); rs[1] += __shfl_xor(rs[1], 32);
        l_run[0] += rs[0]; l_run[1] += rs[1];

        // PV: acc += P . V   (P[qrow][key] from LDS, V^T[dk][key] from Vs)
#pragma unroll
        for (int ks2 = 0; ks2 < 2; ++ks2) {
            bf16x8 pa[2], vb[4];
#pragma unroll
            for (int fm2 = 0; fm2 < 2; ++fm2) {
                int row = fm2 * 16 + (lane & 15);
                int ph = swz(row * 8 + ks2 * 4 + (lane >> 4));
                pa[fm2] = *(const bf16x8*)((const char*)Pw + ph * 16);
            }
#pragma unroll
            for (int fn2 = 0; fn2 < 4; ++fn2) {
                int row = fn2 * 16 + (lane & 15);
                int ph = swz(row * 8 + ks2 * 4 + (lane >> 4));
                vb[fn2] = *(const bf16x8*)((const char*)Vs + ph * 16);
            }
#pragma unroll
            for (int fm2 = 0; fm2 < 2; ++fm2)
#pragma unroll
                for (int fn2 = 0; fn2 < 4; ++fn2)
                    acc[fm2][fn2] = __builtin_amdgcn_mfma_f32_16x16x32_bf16(
                        pa[fm2], vb[fn2], acc[fm2][fn2], 0, 0, 0);
        }
        __syncthreads();
    }

    // epilogue: divide by row-sum, store bf16 to [B,S,H*DK]
    const int b = bh >> 4, h = bh & 15;
#pragma unroll
    for (int fm2 = 0; fm2 < 2; ++fm2) {
        float inv[4];
#pragma unroll
        for (int j = 0; j < 4; ++j) {
            float ls = __shfl(l_run[fm2], (lane >> 4) * 4 + j, 16);
            inv[j] = 1.0f / ls;
        }
#pragma unroll
        for (int fn2 = 0; fn2 < 4; ++fn2)
#pragma unroll
            for (int j = 0; j < 4; ++j) {
                int srow = qt * 128 + w * 32 + fm2 * 16 + (lane >> 4) * 4 + j;
                int col = h * 64 + fn2 * 16 + (lane & 15);
                ao[((size_t)b * S_ + srow) * D_ + col] = f2bf(acc[fm2][fn2][j] * inv[j]);
            }
    }
}

// ---------------------------------------------------------------- launch
extern "C" void kernel_launch(void* const* d_in, const int* in_sizes, int n_in,
                              void* d_out, int out_size, void* d_ws, size_t ws_size,
                              hipStream_t stream) {
    const float* q  = (const float*)d_in[0];
    const float* k  = (const float*)d_in[1];
    const float* v  = (const float*)d_in[2];
    const float* Wq = (const float*)d_in[3];
    const float* bq = (const float*)d_in[4];
    const float* Wk = (const float*)d_in[5];
    const float* bk = (const float*)d_in[6];
    const float* Wv = (const float*)d_in[7];
    const float* bv = (const float*)d_in[8];
    const float* Wo = (const float*)d_in[9];
    const float* bo = (const float*)d_in[10];

    char* ws = (char*)d_ws;
    // layout (56 MiB total):
    u16* qb  = (u16*)(ws);                  // 8 MiB   (reused as Vt later)
    u16* kb  = (u16*)(ws + (8u  << 20));    // 8 MiB   (reused as attn-out later)
    u16* vb  = (u16*)(ws + (16u << 20));    // 8 MiB
    u16* Wqb = (u16*)(ws + (24u << 20));    // 2 MiB
    u16* Wkb = (u16*)(ws + (26u << 20));
    u16* Wvb = (u16*)(ws + (28u << 20));
    u16* Wob = (u16*)(ws + (30u << 20));
    u16* qhb = (u16*)(ws + (32u << 20));    // 8 MiB [B,H,S,DK]
    u16* khb = (u16*)(ws + (40u << 20));
    u16* vhb = (u16*)(ws + (48u << 20));
    u16* Vtb = qb;                          // alias: qb dead after qkv_proj
    u16* aob = kb;                          // alias: kb dead after qkv_proj

    cast_kernel<<<2048, 256, 0, stream>>>(q, qb, B_*S_*D_);
    cast_kernel<<<2048, 256, 0, stream>>>(k, kb, B_*S_*D_);
    cast_kernel<<<2048, 256, 0, stream>>>(v, vb, B_*S_*D_);
    cast_kernel<<<512, 256, 0, stream>>>(Wq, Wqb, D_*D_);
    cast_kernel<<<512, 256, 0, stream>>>(Wk, Wkb, D_*D_);
    cast_kernel<<<512, 256, 0, stream>>>(Wv, Wvb, D_*D_);
    cast_kernel<<<512, 256, 0, stream>>>(Wo, Wob, D_*D_);

    qkv_proj_kernel<<<dim3(256, 3), 256, 0, stream>>>(
        qb, kb, vb, Wqb, Wkb, Wvb, bq, bk, bv, qhb, khb, vhb);

    transpose_v_kernel<<<1024, 256, 0, stream>>>(vhb, Vtb);

    attn_kernel<<<512, 256, 0, stream>>>(qhb, khb, Vtb, aob);

    oproj_kernel<<<256, 256, 0, stream>>>(aob, Wob, bo, (float*)d_out);
}

// Round 3
// 151.265 us; speedup vs baseline: 1.0780x; 1.0780x over previous
//
#include <hip/hip_runtime.h>
#include <stdint.h>

// Problem constants
#define B_  2
#define S_  2048
#define D_  1024
#define H_  16
#define DK_ 64

typedef unsigned short u16;
typedef __attribute__((ext_vector_type(8))) __bf16 bf16x8;
typedef __attribute__((ext_vector_type(4))) float f32x4;
typedef __attribute__((ext_vector_type(4))) short short4v;
typedef __attribute__((ext_vector_type(8))) short short8v;

// f32 -> bf16 round-to-nearest-even
static __device__ __forceinline__ u16 f2bf(float f) {
    union { float f; uint32_t u; } v; v.f = f;
    return (u16)((v.u + 0x7fffu + ((v.u >> 16) & 1u)) >> 16);
}
// pack two f32 -> bf16x2 (RNE), manual
static __device__ __forceinline__ uint32_t pk2bf(float x, float y) {
    return (uint32_t)f2bf(x) | ((uint32_t)f2bf(y) << 16);
}
// raw 2^x
static __device__ __forceinline__ float exp2f_fast(float x) {
    float r; asm("v_exp_f32 %0, %1" : "=v"(r) : "v"(x)); return r;
}

// async global->LDS, 16B per lane. LDS dest = wave-uniform base + lane*16.
#define GLOAD16(gp, lp) \
    __builtin_amdgcn_global_load_lds((const __attribute__((address_space(1))) void*)(gp), \
                                     (__attribute__((address_space(3))) void*)(lp), 16, 0, 0)

// Universal LDS 16B-slot swizzle: phys = lin ^ ((lin>>3)&7). Involution.
static __device__ __forceinline__ int swz(int lin) { return lin ^ ((lin >> 3) & 7); }

// ------------------------------------------------------------- fused cast
// 8192 blocks: q/k/v 2048 each, weights 512 each. 2048 f32 per block.
__global__ __launch_bounds__(256) void cast_all_kernel(
        const float* __restrict__ q, const float* __restrict__ k, const float* __restrict__ v,
        const float* __restrict__ Wq, const float* __restrict__ Wk,
        const float* __restrict__ Wv, const float* __restrict__ Wo,
        u16* __restrict__ qb, u16* __restrict__ kb, u16* __restrict__ vb,
        u16* __restrict__ Wqb, u16* __restrict__ Wkb, u16* __restrict__ Wvb,
        u16* __restrict__ Wob) {
    int blk = blockIdx.x;
    const float* src; u16* dst; int off;
    if (blk < 2048)      { src = q;  dst = qb;  off = blk; }
    else if (blk < 4096) { src = k;  dst = kb;  off = blk - 2048; }
    else if (blk < 6144) { src = v;  dst = vb;  off = blk - 4096; }
    else if (blk < 6656) { src = Wq; dst = Wqb; off = blk - 6144; }
    else if (blk < 7168) { src = Wk; dst = Wkb; off = blk - 6656; }
    else if (blk < 7680) { src = Wv; dst = Wvb; off = blk - 7168; }
    else                 { src = Wo; dst = Wob; off = blk - 7680; }
    int i = (off * 256 + threadIdx.x) * 8;
    float4 a = *(const float4*)(src + i);
    float4 b = *(const float4*)(src + i + 4);
    uint4 r;
    r.x = pk2bf(a.x, a.y); r.y = pk2bf(a.z, a.w);
    r.z = pk2bf(b.x, b.y); r.w = pk2bf(b.z, b.w);
    *(uint4*)(void*)(dst + i) = r;
}

// ------------------------------------------- 128x128 GEMM tile, 2-phase dbuf
// C[m][n] = sum_k X[m][k]*W[n][k]. BK=32, 4 waves (2x2), 16 MFMA/wave/K-step.
// lds: 32KB = As[2][4096] @0, Bs[2][4096] @8192.
__device__ __forceinline__ void gemm128_compute(
        const u16* __restrict__ X, const u16* __restrict__ W,
        int m0, int n0, u16* lds, f32x4 acc[4][4]) {
    const int tid = threadIdx.x, lane = tid & 63, w = tid >> 6;
    const int wm = w >> 1, wn = w & 1;
    u16* As = lds;
    u16* Bs = lds + 8192;

    auto stage = [&](int bi, int kt) {
#pragma unroll
        for (int r = 0; r < 2; ++r) {
            int s = tid + (r << 8);
            int lin = s ^ ((s >> 3) & 7);       // inverse swizzle (involution)
            int row = lin >> 2, ch = lin & 3;   // 64B rows: 4 chunks of 16B
            GLOAD16(X + (size_t)(m0 + row) * 1024 + (kt << 5) + (ch << 3),
                    (char*)(As + bi * 4096) + ((r << 8) + (w << 6)) * 16);
            GLOAD16(W + (size_t)(n0 + row) * 1024 + (kt << 5) + (ch << 3),
                    (char*)(Bs + bi * 4096) + ((r << 8) + (w << 6)) * 16);
        }
    };

    stage(0, 0);
    asm volatile("s_waitcnt vmcnt(0)" ::: "memory");
    __syncthreads();
#pragma unroll 1
    for (int kt = 0; kt < 32; ++kt) {
        const int cur = kt & 1;
        if (kt < 31) stage(cur ^ 1, kt + 1);    // prefetch next tile (in flight)
        const char* Ab = (const char*)(As + cur * 4096);
        const char* Bb = (const char*)(Bs + cur * 4096);
        bf16x8 a[4], b[4];
#pragma unroll
        for (int f = 0; f < 4; ++f) {
            int rowa = wm * 64 + f * 16 + (lane & 15);
            a[f] = *(const bf16x8*)(Ab + swz(rowa * 4 + (lane >> 4)) * 16);
            int rowb = wn * 64 + f * 16 + (lane & 15);
            b[f] = *(const bf16x8*)(Bb + swz(rowb * 4 + (lane >> 4)) * 16);
        }
#pragma unroll
        for (int fm = 0; fm < 4; ++fm)
#pragma unroll
            for (int fn = 0; fn < 4; ++fn)
                acc[fm][fn] = __builtin_amdgcn_mfma_f32_16x16x32_bf16(
                    a[fm], b[fn], acc[fm][fn], 0, 0, 0);
        __syncthreads();   // drains vmcnt (prefetch landed) + lgkm, guards buf reuse
    }
}

// QKV projection fused over blockIdx.y. Q/K: heads layout [B,H,S,DK] (Q
// pre-scaled by log2(e)/sqrt(DK) for exp2 softmax). V: transposed store
// [BH,DK,S] through LDS (replaces separate transpose kernel).
__global__ __launch_bounds__(256) void qkv_proj_kernel(
        const u16* __restrict__ qX, const u16* __restrict__ kX, const u16* __restrict__ vX,
        const u16* __restrict__ Wq, const u16* __restrict__ Wk, const u16* __restrict__ Wv,
        const float* __restrict__ bq, const float* __restrict__ bk, const float* __restrict__ bv,
        u16* __restrict__ qo, u16* __restrict__ ko, u16* __restrict__ vt) {
    __shared__ __align__(16) u16 lds[16384];
    const int which = blockIdx.y;
    const u16* X = which == 0 ? qX : (which == 1 ? kX : vX);
    const u16* W = which == 0 ? Wq : (which == 1 ? Wk : Wv);
    const float* bias = which == 0 ? bq : (which == 1 ? bk : bv);

    const int bid = blockIdx.x;
    const int m0 = (bid >> 3) << 7;
    const int n0 = (bid & 7) << 7;
    f32x4 acc[4][4] = {};
    gemm128_compute(X, W, m0, n0, lds, acc);

    const int tid = threadIdx.x, lane = tid & 63, w = tid >> 6;
    const int wm = w >> 1, wn = w & 1;

    if (which < 2) {
        u16* out = which == 0 ? qo : ko;
        const float scale = which == 0 ? 0.1803368801111883f : 1.0f; // (1/8)*log2(e)
#pragma unroll
        for (int fn = 0; fn < 4; ++fn) {
            int n = n0 + wn * 64 + fn * 16 + (lane & 15);
            float bb = bias[n];
            int h = n >> 6, dk = n & 63;
#pragma unroll
            for (int fm = 0; fm < 4; ++fm)
#pragma unroll
                for (int j = 0; j < 4; ++j) {
                    int m = m0 + wm * 64 + fm * 16 + (lane >> 4) * 4 + j;
                    int b = m >> 11, s = m & 2047;
                    out[((size_t)(b * H_ + h) * S_ + s) * DK_ + dk] =
                        f2bf((acc[fm][fn][j] + bb) * scale);
                }
        }
    } else {
        // V: per 64-col half (= one head), transpose [128 s][64 dk] -> [64 dk][128 s]
        // via LDS tile with row stride 136 (16B-aligned rows, 2-way-free banks).
        const int b = m0 >> 11, sbase = m0 & 2047;
        for (int nh = 0; nh < 2; ++nh) {
            __syncthreads();
            if (wn == nh) {
#pragma unroll
                for (int fn = 0; fn < 4; ++fn) {
                    int np = fn * 16 + (lane & 15);          // dk within head
                    float bb = bias[n0 + nh * 64 + np];
#pragma unroll
                    for (int fm = 0; fm < 4; ++fm) {
                        int mp0 = wm * 64 + fm * 16 + (lane >> 4) * 4;  // s within tile
                        short4v p;
#pragma unroll
                        for (int j = 0; j < 4; ++j)
                            p[j] = (short)f2bf(acc[fm][fn][j] + bb);
                        *(short4v*)(void*)&lds[np * 136 + mp0] = p;
                    }
                }
            }
            __syncthreads();
            int dk = tid >> 2, t4 = tid & 3;
            int h = (n0 >> 6) + nh;
            u16* dst = vt + ((size_t)((b * H_ + h) * DK_ + dk)) * S_ + sbase;
#pragma unroll
            for (int c = 0; c < 4; ++c) {
                int so = t4 * 8 + c * 32;
                *(short8v*)(void*)(dst + so) =
                    *(const short8v*)(const void*)&lds[dk * 136 + so];
            }
        }
    }
}

// Output projection: bf16 attn-out @ Wo^T + bo -> fp32 d_out
__global__ __launch_bounds__(256) void oproj_kernel(
        const u16* __restrict__ X, const u16* __restrict__ W,
        const float* __restrict__ bias, float* __restrict__ out) {
    __shared__ __align__(16) u16 lds[16384];
    const int bid = blockIdx.x;
    const int m0 = (bid >> 3) << 7;
    const int n0 = (bid & 7) << 7;
    f32x4 acc[4][4] = {};
    gemm128_compute(X, W, m0, n0, lds, acc);

    const int lane = threadIdx.x & 63, w = threadIdx.x >> 6;
    const int wm = w >> 1, wn = w & 1;
#pragma unroll
    for (int fn = 0; fn < 4; ++fn) {
        int n = n0 + wn * 64 + fn * 16 + (lane & 15);
        float bb = bias[n];
#pragma unroll
        for (int fm = 0; fm < 4; ++fm)
#pragma unroll
            for (int j = 0; j < 4; ++j) {
                int m = m0 + wm * 64 + fm * 16 + (lane >> 4) * 4 + j;
                out[(size_t)m * 1024 + n] = acc[fm][fn][j] + bb;
            }
    }
}

// ------------------------------------------------------------ flash attention
// Per block: one (b,h), 128 q-rows, 4 waves x 32 rows. KV tiles of 64,
// 2-phase double-buffered staging. Swapped QK^T; exp2 softmax (scale folded
// into Q); P staged via per-wave LDS; PV from V^T tiles.
__global__ __launch_bounds__(256) void attn_kernel(
        const u16* __restrict__ qh, const u16* __restrict__ kh,
        const u16* __restrict__ Vt, u16* __restrict__ ao) {
    __shared__ __align__(16) u16 Qs[8192];       // 16KB
    __shared__ __align__(16) u16 Ks[2][4096];    // 16KB dbuf
    __shared__ __align__(16) u16 Vs[2][4096];    // 16KB dbuf
    __shared__ __align__(16) u16 Ps[8192];       // 16KB, per-wave 2048

    const int tid = threadIdx.x, lane = tid & 63, w = tid >> 6;
    const int bh = blockIdx.x >> 4, qt = blockIdx.x & 15;
    const u16* qg = qh + ((size_t)bh * S_ + qt * 128) * DK_;
    const u16* kg = kh + (size_t)bh * S_ * DK_;
    const u16* vg = Vt + (size_t)bh * DK_ * S_;

    auto stageKV = [&](int bi, int kt) {
#pragma unroll
        for (int r = 0; r < 2; ++r) {
            int s = tid + (r << 8);
            int lin = s ^ ((s >> 3) & 7);
            int row = lin >> 3, ch = lin & 7;    // 128B rows: 8 chunks
            GLOAD16(kg + (size_t)(kt * 64 + row) * 64 + (ch << 3),
                    (char*)(&Ks[bi][0]) + ((r << 8) + (w << 6)) * 16);
            GLOAD16(vg + (size_t)row * S_ + kt * 64 + (ch << 3),
                    (char*)(&Vs[bi][0]) + ((r << 8) + (w << 6)) * 16);
        }
    };

    // prologue: stage Q tile + KV tile 0
#pragma unroll
    for (int r = 0; r < 4; ++r) {
        int s = tid + (r << 8);
        int lin = s ^ ((s >> 3) & 7);
        int row = lin >> 3, ch = lin & 7;
        GLOAD16(qg + row * 64 + (ch << 3), (char*)Qs + ((r << 8) + (w << 6)) * 16);
    }
    stageKV(0, 0);
    asm volatile("s_waitcnt vmcnt(0)" ::: "memory");
    __syncthreads();

    // Q fragments (B-operand): qrow = w*32+fn*16+(l&15)
    bf16x8 qf[2][2];
#pragma unroll
    for (int fn = 0; fn < 2; ++fn)
#pragma unroll
        for (int ks = 0; ks < 2; ++ks) {
            int row = w * 32 + fn * 16 + (lane & 15);
            qf[fn][ks] = *(const bf16x8*)((const char*)Qs +
                          swz(row * 8 + ks * 4 + (lane >> 4)) * 16);
        }

    f32x4 acc[2][4] = {};
    float l_run[2] = {0.f, 0.f};
    u16* Pw = Ps + w * 2048;

#pragma unroll 1
    for (int kt = 0; kt < 32; ++kt) {
        const int cur = kt & 1;
        if (kt < 31) stageKV(cur ^ 1, kt + 1);   // prefetch next KV tile
        const char* Kb = (const char*)&Ks[cur][0];
        const char* Vb = (const char*)&Vs[cur][0];

        // St = K . Q^T
        f32x4 st[4][2] = {};
#pragma unroll
        for (int ks = 0; ks < 2; ++ks) {
            bf16x8 kf[4];
#pragma unroll
            for (int fm = 0; fm < 4; ++fm) {
                int row = fm * 16 + (lane & 15);
                kf[fm] = *(const bf16x8*)(Kb + swz(row * 8 + ks * 4 + (lane >> 4)) * 16);
            }
            __builtin_amdgcn_s_setprio(1);
#pragma unroll
            for (int fm = 0; fm < 4; ++fm)
#pragma unroll
                for (int fn = 0; fn < 2; ++fn)
                    st[fm][fn] = __builtin_amdgcn_mfma_f32_16x16x32_bf16(
                        kf[fm], qf[fn][ks], st[fm][fn], 0, 0, 0);
            __builtin_amdgcn_s_setprio(0);
        }

        // softmax numerator (exp2; scale pre-folded into Q) + P pack to LDS
        float rs[2] = {0.f, 0.f};
#pragma unroll
        for (int fm = 0; fm < 4; ++fm)
#pragma unroll
            for (int fn = 0; fn < 2; ++fn) {
                float e0 = exp2f_fast(st[fm][fn][0]);
                float e1 = exp2f_fast(st[fm][fn][1]);
                float e2 = exp2f_fast(st[fm][fn][2]);
                float e3 = exp2f_fast(st[fm][fn][3]);
                rs[fn] += (e0 + e1) + (e2 + e3);
                uint2 pk; pk.x = pk2bf(e0, e1); pk.y = pk2bf(e2, e3);
                int qrow = fn * 16 + (lane & 15);
                int g = lane >> 4;
                int slot = qrow * 8 + fm * 2 + (g >> 1);
                int ph = slot ^ (qrow & 7);
                *(uint2*)((char*)Pw + ph * 16 + (g & 1) * 8) = pk;
            }
        rs[0] += __shfl_xor(rs[0], 16); rs[0] += __shfl_xor(rs[0], 32);
        rs[1] += __shfl_xor(rs[1], 16); rs[1] += __shfl_xor(rs[1], 32);
        l_run[0] += rs[0]; l_run[1] += rs[1];

        // PV: acc += P . V
#pragma unroll
        for (int ks2 = 0; ks2 < 2; ++ks2) {
            bf16x8 pa[2], vb2[4];
#pragma unroll
            for (int fm2 = 0; fm2 < 2; ++fm2) {
                int row = fm2 * 16 + (lane & 15);
                pa[fm2] = *(const bf16x8*)((const char*)Pw +
                            swz(row * 8 + ks2 * 4 + (lane >> 4)) * 16);
            }
#pragma unroll
            for (int fn2 = 0; fn2 < 4; ++fn2) {
                int row = fn2 * 16 + (lane & 15);
                vb2[fn2] = *(const bf16x8*)(Vb + swz(row * 8 + ks2 * 4 + (lane >> 4)) * 16);
            }
            __builtin_amdgcn_s_setprio(1);
#pragma unroll
            for (int fm2 = 0; fm2 < 2; ++fm2)
#pragma unroll
                for (int fn2 = 0; fn2 < 4; ++fn2)
                    acc[fm2][fn2] = __builtin_amdgcn_mfma_f32_16x16x32_bf16(
                        pa[fm2], vb2[fn2], acc[fm2][fn2], 0, 0, 0);
            __builtin_amdgcn_s_setprio(0);
        }
        __syncthreads();   // drains prefetch vmcnt + lgkm, guards dbuf reuse
    }

    // epilogue: divide by row-sum, store bf16 to [B,S,H*DK]
    const int b = bh >> 4, h = bh & 15;
#pragma unroll
    for (int fm2 = 0; fm2 < 2; ++fm2) {
        float inv[4];
#pragma unroll
        for (int j = 0; j < 4; ++j)
            inv[j] = 1.0f / __shfl(l_run[fm2], (lane >> 4) * 4 + j, 16);
#pragma unroll
        for (int fn2 = 0; fn2 < 4; ++fn2)
#pragma unroll
            for (int j = 0; j < 4; ++j) {
                int srow = qt * 128 + w * 32 + fm2 * 16 + (lane >> 4) * 4 + j;
                int col = h * 64 + fn2 * 16 + (lane & 15);
                ao[((size_t)b * S_ + srow) * D_ + col] = f2bf(acc[fm2][fn2][j] * inv[j]);
            }
    }
}

// ---------------------------------------------------------------- launch
extern "C" void kernel_launch(void* const* d_in, const int* in_sizes, int n_in,
                              void* d_out, int out_size, void* d_ws, size_t ws_size,
                              hipStream_t stream) {
    const float* q  = (const float*)d_in[0];
    const float* k  = (const float*)d_in[1];
    const float* v  = (const float*)d_in[2];
    const float* Wq = (const float*)d_in[3];
    const float* bq = (const float*)d_in[4];
    const float* Wk = (const float*)d_in[5];
    const float* bk = (const float*)d_in[6];
    const float* Wv = (const float*)d_in[7];
    const float* bv = (const float*)d_in[8];
    const float* Wo = (const float*)d_in[9];
    const float* bo = (const float*)d_in[10];

    char* ws = (char*)d_ws;
    u16* qb  = (u16*)(ws);                  // 8 MiB
    u16* kb  = (u16*)(ws + (8u  << 20));    // 8 MiB (reused as attn-out)
    u16* vb  = (u16*)(ws + (16u << 20));    // 8 MiB
    u16* Wqb = (u16*)(ws + (24u << 20));    // 2 MiB each
    u16* Wkb = (u16*)(ws + (26u << 20));
    u16* Wvb = (u16*)(ws + (28u << 20));
    u16* Wob = (u16*)(ws + (30u << 20));
    u16* qhb = (u16*)(ws + (32u << 20));    // 8 MiB [B,H,S,DK]
    u16* khb = (u16*)(ws + (40u << 20));    // 8 MiB [B,H,S,DK]
    u16* Vtb = (u16*)(ws + (48u << 20));    // 8 MiB [BH,DK,S]
    u16* aob = kb;                          // alias: kb dead after qkv_proj

    cast_all_kernel<<<8192, 256, 0, stream>>>(q, k, v, Wq, Wk, Wv, Wo,
                                              qb, kb, vb, Wqb, Wkb, Wvb, Wob);

    qkv_proj_kernel<<<dim3(256, 3), 256, 0, stream>>>(
        qb, kb, vb, Wqb, Wkb, Wvb, bq, bk, bv, qhb, khb, Vtb);

    attn_kernel<<<512, 256, 0, stream>>>(qhb, khb, Vtb, aob);

    oproj_kernel<<<256, 256, 0, stream>>>(aob, Wob, bo, (float*)d_out);
}

// Round 4
// 142.347 us; speedup vs baseline: 1.1455x; 1.0626x over previous
//
#include <hip/hip_runtime.h>
#include <stdint.h>

// Problem constants
#define B_  2
#define S_  2048
#define D_  1024
#define H_  16
#define DK_ 64

typedef unsigned short u16;
typedef __attribute__((ext_vector_type(8))) __bf16 bf16x8;
typedef __attribute__((ext_vector_type(4))) float f32x4;
typedef __attribute__((ext_vector_type(4))) short short4v;
typedef __attribute__((ext_vector_type(8))) short short8v;

// f32 -> bf16 round-to-nearest-even (scalar, epilogue use)
static __device__ __forceinline__ u16 f2bf(float f) {
    union { float f; uint32_t u; } v; v.f = f;
    return (u16)((v.u + 0x7fffu + ((v.u >> 16) & 1u)) >> 16);
}
static __device__ __forceinline__ uint32_t pk2bf(float x, float y) {
    return (uint32_t)f2bf(x) | ((uint32_t)f2bf(y) << 16);
}
// HW packed f32x2 -> bf16x2 (RNE) — 1 VALU op (T12 primitive)
static __device__ __forceinline__ uint32_t cvtpk_bf16(float lo, float hi) {
    uint32_t r; asm("v_cvt_pk_bf16_f32 %0, %1, %2" : "=v"(r) : "v"(lo), "v"(hi));
    return r;
}
// raw 2^x
static __device__ __forceinline__ float exp2f_fast(float x) {
    float r; asm("v_exp_f32 %0, %1" : "=v"(r) : "v"(x)); return r;
}

// async global->LDS, 16B per lane. LDS dest = wave-uniform base + lane*16.
#define GLOAD16(gp, lp) \
    __builtin_amdgcn_global_load_lds((const __attribute__((address_space(1))) void*)(gp), \
                                     (__attribute__((address_space(3))) void*)(lp), 16, 0, 0)

// Universal LDS 16B-slot swizzle: phys = lin ^ ((lin>>3)&7). Involution.
static __device__ __forceinline__ int swz(int lin) { return lin ^ ((lin >> 3) & 7); }

// ------------------------------------------------------------- fused cast
__global__ __launch_bounds__(256) void cast_all_kernel(
        const float* __restrict__ q, const float* __restrict__ k, const float* __restrict__ v,
        const float* __restrict__ Wq, const float* __restrict__ Wk,
        const float* __restrict__ Wv, const float* __restrict__ Wo,
        u16* __restrict__ qb, u16* __restrict__ kb, u16* __restrict__ vb,
        u16* __restrict__ Wqb, u16* __restrict__ Wkb, u16* __restrict__ Wvb,
        u16* __restrict__ Wob) {
    int blk = blockIdx.x;
    const float* src; u16* dst; int off;
    if (blk < 2048)      { src = q;  dst = qb;  off = blk; }
    else if (blk < 4096) { src = k;  dst = kb;  off = blk - 2048; }
    else if (blk < 6144) { src = v;  dst = vb;  off = blk - 4096; }
    else if (blk < 6656) { src = Wq; dst = Wqb; off = blk - 6144; }
    else if (blk < 7168) { src = Wk; dst = Wkb; off = blk - 6656; }
    else if (blk < 7680) { src = Wv; dst = Wvb; off = blk - 7168; }
    else                 { src = Wo; dst = Wob; off = blk - 7680; }
    int i = (off * 256 + threadIdx.x) * 8;
    float4 a = *(const float4*)(src + i);
    float4 b = *(const float4*)(src + i + 4);
    uint4 r;
    r.x = pk2bf(a.x, a.y); r.y = pk2bf(a.z, a.w);
    r.z = pk2bf(b.x, b.y); r.w = pk2bf(b.z, b.w);
    *(uint4*)(void*)(dst + i) = r;
}

// ------------------------------------------- 128x128 GEMM tile, 2-phase dbuf
__device__ __forceinline__ void gemm128_compute(
        const u16* __restrict__ X, const u16* __restrict__ W,
        int m0, int n0, u16* lds, f32x4 acc[4][4]) {
    const int tid = threadIdx.x, lane = tid & 63, w = tid >> 6;
    const int wm = w >> 1, wn = w & 1;
    u16* As = lds;
    u16* Bs = lds + 8192;

    auto stage = [&](int bi, int kt) {
#pragma unroll
        for (int r = 0; r < 2; ++r) {
            int s = tid + (r << 8);
            int lin = s ^ ((s >> 3) & 7);       // inverse swizzle (involution)
            int row = lin >> 2, ch = lin & 3;   // 64B rows: 4 chunks of 16B
            GLOAD16(X + (size_t)(m0 + row) * 1024 + (kt << 5) + (ch << 3),
                    (char*)(As + bi * 4096) + ((r << 8) + (w << 6)) * 16);
            GLOAD16(W + (size_t)(n0 + row) * 1024 + (kt << 5) + (ch << 3),
                    (char*)(Bs + bi * 4096) + ((r << 8) + (w << 6)) * 16);
        }
    };

    stage(0, 0);
    asm volatile("s_waitcnt vmcnt(0)" ::: "memory");
    __syncthreads();
#pragma unroll 1
    for (int kt = 0; kt < 32; ++kt) {
        const int cur = kt & 1;
        if (kt < 31) stage(cur ^ 1, kt + 1);    // prefetch next tile (in flight)
        const char* Ab = (const char*)(As + cur * 4096);
        const char* Bb = (const char*)(Bs + cur * 4096);
        bf16x8 a[4], b[4];
#pragma unroll
        for (int f = 0; f < 4; ++f) {
            int rowa = wm * 64 + f * 16 + (lane & 15);
            a[f] = *(const bf16x8*)(Ab + swz(rowa * 4 + (lane >> 4)) * 16);
            int rowb = wn * 64 + f * 16 + (lane & 15);
            b[f] = *(const bf16x8*)(Bb + swz(rowb * 4 + (lane >> 4)) * 16);
        }
#pragma unroll
        for (int fm = 0; fm < 4; ++fm)
#pragma unroll
            for (int fn = 0; fn < 4; ++fn)
                acc[fm][fn] = __builtin_amdgcn_mfma_f32_16x16x32_bf16(
                    a[fm], b[fn], acc[fm][fn], 0, 0, 0);
        __syncthreads();   // drains vmcnt (prefetch landed) + lgkm, guards buf reuse
    }
}

// QKV projection fused over blockIdx.y. Q/K -> [B,H,S,DK] (Q pre-scaled by
// log2(e)/sqrt(DK)). V -> transposed [BH,DK,S] via LDS.
__global__ __launch_bounds__(256) void qkv_proj_kernel(
        const u16* __restrict__ qX, const u16* __restrict__ kX, const u16* __restrict__ vX,
        const u16* __restrict__ Wq, const u16* __restrict__ Wk, const u16* __restrict__ Wv,
        const float* __restrict__ bq, const float* __restrict__ bk, const float* __restrict__ bv,
        u16* __restrict__ qo, u16* __restrict__ ko, u16* __restrict__ vt) {
    __shared__ __align__(16) u16 lds[16384];
    const int which = blockIdx.y;
    const u16* X = which == 0 ? qX : (which == 1 ? kX : vX);
    const u16* W = which == 0 ? Wq : (which == 1 ? Wk : Wv);
    const float* bias = which == 0 ? bq : (which == 1 ? bk : bv);

    const int bid = blockIdx.x;
    const int m0 = (bid >> 3) << 7;
    const int n0 = (bid & 7) << 7;
    f32x4 acc[4][4] = {};
    gemm128_compute(X, W, m0, n0, lds, acc);

    const int tid = threadIdx.x, lane = tid & 63, w = tid >> 6;
    const int wm = w >> 1, wn = w & 1;

    if (which < 2) {
        u16* out = which == 0 ? qo : ko;
        const float scale = which == 0 ? 0.1803368801111883f : 1.0f; // (1/8)*log2(e)
#pragma unroll
        for (int fn = 0; fn < 4; ++fn) {
            int n = n0 + wn * 64 + fn * 16 + (lane & 15);
            float bb = bias[n];
            int h = n >> 6, dk = n & 63;
#pragma unroll
            for (int fm = 0; fm < 4; ++fm)
#pragma unroll
                for (int j = 0; j < 4; ++j) {
                    int m = m0 + wm * 64 + fm * 16 + (lane >> 4) * 4 + j;
                    int b = m >> 11, s = m & 2047;
                    out[((size_t)(b * H_ + h) * S_ + s) * DK_ + dk] =
                        f2bf((acc[fm][fn][j] + bb) * scale);
                }
        }
    } else {
        // V: per 64-col half (= one head), transpose [128 s][64 dk] -> [64 dk][128 s]
        const int b = m0 >> 11, sbase = m0 & 2047;
        for (int nh = 0; nh < 2; ++nh) {
            __syncthreads();
            if (wn == nh) {
#pragma unroll
                for (int fn = 0; fn < 4; ++fn) {
                    int np = fn * 16 + (lane & 15);          // dk within head
                    float bb = bias[n0 + nh * 64 + np];
#pragma unroll
                    for (int fm = 0; fm < 4; ++fm) {
                        int mp0 = wm * 64 + fm * 16 + (lane >> 4) * 4;  // s within tile
                        short4v p;
#pragma unroll
                        for (int j = 0; j < 4; ++j)
                            p[j] = (short)f2bf(acc[fm][fn][j] + bb);
                        *(short4v*)(void*)&lds[np * 136 + mp0] = p;
                    }
                }
            }
            __syncthreads();
            int dk = tid >> 2, t4 = tid & 3;
            int h = (n0 >> 6) + nh;
            u16* dst = vt + ((size_t)((b * H_ + h) * DK_ + dk)) * S_ + sbase;
#pragma unroll
            for (int c = 0; c < 4; ++c) {
                int so = t4 * 8 + c * 32;
                *(short8v*)(void*)(dst + so) =
                    *(const short8v*)(const void*)&lds[dk * 136 + so];
            }
        }
    }
}

// Output projection: bf16 attn-out @ Wo^T + bo -> fp32 d_out
__global__ __launch_bounds__(256) void oproj_kernel(
        const u16* __restrict__ X, const u16* __restrict__ W,
        const float* __restrict__ bias, float* __restrict__ out) {
    __shared__ __align__(16) u16 lds[16384];
    const int bid = blockIdx.x;
    const int m0 = (bid >> 3) << 7;
    const int n0 = (bid & 7) << 7;
    f32x4 acc[4][4] = {};
    gemm128_compute(X, W, m0, n0, lds, acc);

    const int lane = threadIdx.x & 63, w = threadIdx.x >> 6;
    const int wm = w >> 1, wn = w & 1;
#pragma unroll
    for (int fn = 0; fn < 4; ++fn) {
        int n = n0 + wn * 64 + fn * 16 + (lane & 15);
        float bb = bias[n];
#pragma unroll
        for (int fm = 0; fm < 4; ++fm)
#pragma unroll
            for (int j = 0; j < 4; ++j) {
                int m = m0 + wm * 64 + fm * 16 + (lane >> 4) * 4 + j;
                out[(size_t)m * 1024 + n] = acc[fm][fn][j] + bb;
            }
    }
}

// ------------------------------------------------------------ flash attention
// Per block: one (b,h), 128 q-rows, 4 waves x 32 rows. KV tiles of 64.
// Swapped QK^T; exp2 softmax (scale folded into Q); P packed with
// v_cvt_pk_bf16_f32; row-sum via MFMA-with-ones (VALU -> MFMA pipe).
__global__ __launch_bounds__(256) void attn_kernel(
        const u16* __restrict__ qh, const u16* __restrict__ kh,
        const u16* __restrict__ Vt, u16* __restrict__ ao) {
    __shared__ __align__(16) u16 Qs[8192];       // 16KB
    __shared__ __align__(16) u16 Ks[2][4096];    // 16KB dbuf
    __shared__ __align__(16) u16 Vs[2][4096];    // 16KB dbuf
    __shared__ __align__(16) u16 Ps[8192];       // 16KB, per-wave 2048

    const int tid = threadIdx.x, lane = tid & 63, w = tid >> 6;
    const int bh = blockIdx.x >> 4, qt = blockIdx.x & 15;
    const u16* qg = qh + ((size_t)bh * S_ + qt * 128) * DK_;
    const u16* kg = kh + (size_t)bh * S_ * DK_;
    const u16* vg = Vt + (size_t)bh * DK_ * S_;

    auto stageKV = [&](int bi, int kt) {
#pragma unroll
        for (int r = 0; r < 2; ++r) {
            int s = tid + (r << 8);
            int lin = s ^ ((s >> 3) & 7);
            int row = lin >> 3, ch = lin & 7;    // 128B rows: 8 chunks
            GLOAD16(kg + (size_t)(kt * 64 + row) * 64 + (ch << 3),
                    (char*)(&Ks[bi][0]) + ((r << 8) + (w << 6)) * 16);
            GLOAD16(vg + (size_t)row * S_ + kt * 64 + (ch << 3),
                    (char*)(&Vs[bi][0]) + ((r << 8) + (w << 6)) * 16);
        }
    };

    // prologue: stage Q tile + KV tile 0
#pragma unroll
    for (int r = 0; r < 4; ++r) {
        int s = tid + (r << 8);
        int lin = s ^ ((s >> 3) & 7);
        int row = lin >> 3, ch = lin & 7;
        GLOAD16(qg + row * 64 + (ch << 3), (char*)Qs + ((r << 8) + (w << 6)) * 16);
    }
    stageKV(0, 0);
    asm volatile("s_waitcnt vmcnt(0)" ::: "memory");
    __syncthreads();

    // Q fragments (B-operand): qrow = w*32+fn*16+(l&15)
    bf16x8 qf[2][2];
#pragma unroll
    for (int fn = 0; fn < 2; ++fn)
#pragma unroll
        for (int ks = 0; ks < 2; ++ks) {
            int row = w * 32 + fn * 16 + (lane & 15);
            qf[fn][ks] = *(const bf16x8*)((const char*)Qs +
                          swz(row * 8 + ks * 4 + (lane >> 4)) * 16);
        }

    // all-ones bf16 B-operand for the row-sum MFMA
    union { short8v s; bf16x8 b; } onesu;
#pragma unroll
    for (int i = 0; i < 8; ++i) onesu.s[i] = 0x3F80;
    const bf16x8 onesf = onesu.b;

    f32x4 acc[2][4] = {};
    f32x4 accl[2] = {};          // row-sum accumulator, same D-layout rows as acc
    u16* Pw = Ps + w * 2048;

#pragma unroll 1
    for (int kt = 0; kt < 32; ++kt) {
        const int cur = kt & 1;
        if (kt < 31) stageKV(cur ^ 1, kt + 1);   // prefetch next KV tile
        const char* Kb = (const char*)&Ks[cur][0];
        const char* Vb = (const char*)&Vs[cur][0];

        // St = K . Q^T
        f32x4 st[4][2] = {};
#pragma unroll
        for (int ks = 0; ks < 2; ++ks) {
            bf16x8 kf[4];
#pragma unroll
            for (int fm = 0; fm < 4; ++fm) {
                int row = fm * 16 + (lane & 15);
                kf[fm] = *(const bf16x8*)(Kb + swz(row * 8 + ks * 4 + (lane >> 4)) * 16);
            }
            __builtin_amdgcn_s_setprio(1);
#pragma unroll
            for (int fm = 0; fm < 4; ++fm)
#pragma unroll
                for (int fn = 0; fn < 2; ++fn)
                    st[fm][fn] = __builtin_amdgcn_mfma_f32_16x16x32_bf16(
                        kf[fm], qf[fn][ks], st[fm][fn], 0, 0, 0);
            __builtin_amdgcn_s_setprio(0);
        }

        // softmax numerator (exp2) + P pack via v_cvt_pk_bf16_f32
#pragma unroll
        for (int fm = 0; fm < 4; ++fm)
#pragma unroll
            for (int fn = 0; fn < 2; ++fn) {
                float e0 = exp2f_fast(st[fm][fn][0]);
                float e1 = exp2f_fast(st[fm][fn][1]);
                float e2 = exp2f_fast(st[fm][fn][2]);
                float e3 = exp2f_fast(st[fm][fn][3]);
                uint2 pk; pk.x = cvtpk_bf16(e0, e1); pk.y = cvtpk_bf16(e2, e3);
                int qrow = fn * 16 + (lane & 15);
                int g = lane >> 4;
                int slot = qrow * 8 + fm * 2 + (g >> 1);
                int ph = slot ^ (qrow & 7);
                *(uint2*)((char*)Pw + ph * 16 + (g & 1) * 8) = pk;
            }

        // PV: acc += P . V ; accl += P . 1 (row-sum on the MFMA pipe)
#pragma unroll
        for (int ks2 = 0; ks2 < 2; ++ks2) {
            bf16x8 pa[2], vb2[4];
#pragma unroll
            for (int fm2 = 0; fm2 < 2; ++fm2) {
                int row = fm2 * 16 + (lane & 15);
                pa[fm2] = *(const bf16x8*)((const char*)Pw +
                            swz(row * 8 + ks2 * 4 + (lane >> 4)) * 16);
            }
#pragma unroll
            for (int fn2 = 0; fn2 < 4; ++fn2) {
                int row = fn2 * 16 + (lane & 15);
                vb2[fn2] = *(const bf16x8*)(Vb + swz(row * 8 + ks2 * 4 + (lane >> 4)) * 16);
            }
            __builtin_amdgcn_s_setprio(1);
#pragma unroll
            for (int fm2 = 0; fm2 < 2; ++fm2) {
#pragma unroll
                for (int fn2 = 0; fn2 < 4; ++fn2)
                    acc[fm2][fn2] = __builtin_amdgcn_mfma_f32_16x16x32_bf16(
                        pa[fm2], vb2[fn2], acc[fm2][fn2], 0, 0, 0);
                accl[fm2] = __builtin_amdgcn_mfma_f32_16x16x32_bf16(
                    pa[fm2], onesf, accl[fm2], 0, 0, 0);
            }
            __builtin_amdgcn_s_setprio(0);
        }
        __syncthreads();   // drains prefetch vmcnt + lgkm, guards dbuf reuse
    }

    // epilogue: divide by row-sum (already in matching row layout), store bf16
    const int b = bh >> 4, h = bh & 15;
#pragma unroll
    for (int fm2 = 0; fm2 < 2; ++fm2) {
        float inv[4];
#pragma unroll
        for (int j = 0; j < 4; ++j)
            inv[j] = 1.0f / accl[fm2][j];
#pragma unroll
        for (int fn2 = 0; fn2 < 4; ++fn2)
#pragma unroll
            for (int j = 0; j < 4; ++j) {
                int srow = qt * 128 + w * 32 + fm2 * 16 + (lane >> 4) * 4 + j;
                int col = h * 64 + fn2 * 16 + (lane & 15);
                ao[((size_t)b * S_ + srow) * D_ + col] = f2bf(acc[fm2][fn2][j] * inv[j]);
            }
    }
}

// ---------------------------------------------------------------- launch
extern "C" void kernel_launch(void* const* d_in, const int* in_sizes, int n_in,
                              void* d_out, int out_size, void* d_ws, size_t ws_size,
                              hipStream_t stream) {
    const float* q  = (const float*)d_in[0];
    const float* k  = (const float*)d_in[1];
    const float* v  = (const float*)d_in[2];
    const float* Wq = (const float*)d_in[3];
    const float* bq = (const float*)d_in[4];
    const float* Wk = (const float*)d_in[5];
    const float* bk = (const float*)d_in[6];
    const float* Wv = (const float*)d_in[7];
    const float* bv = (const float*)d_in[8];
    const float* Wo = (const float*)d_in[9];
    const float* bo = (const float*)d_in[10];

    char* ws = (char*)d_ws;
    u16* qb  = (u16*)(ws);                  // 8 MiB
    u16* kb  = (u16*)(ws + (8u  << 20));    // 8 MiB (reused as attn-out)
    u16* vb  = (u16*)(ws + (16u << 20));    // 8 MiB
    u16* Wqb = (u16*)(ws + (24u << 20));    // 2 MiB each
    u16* Wkb = (u16*)(ws + (26u << 20));
    u16* Wvb = (u16*)(ws + (28u << 20));
    u16* Wob = (u16*)(ws + (30u << 20));
    u16* qhb = (u16*)(ws + (32u << 20));    // 8 MiB [B,H,S,DK]
    u16* khb = (u16*)(ws + (40u << 20));    // 8 MiB [B,H,S,DK]
    u16* Vtb = (u16*)(ws + (48u << 20));    // 8 MiB [BH,DK,S]
    u16* aob = kb;                          // alias: kb dead after qkv_proj

    cast_all_kernel<<<8192, 256, 0, stream>>>(q, k, v, Wq, Wk, Wv, Wo,
                                              qb, kb, vb, Wqb, Wkb, Wvb, Wob);

    qkv_proj_kernel<<<dim3(256, 3), 256, 0, stream>>>(
        qb, kb, vb, Wqb, Wkb, Wvb, bq, bk, bv, qhb, khb, Vtb);

    attn_kernel<<<512, 256, 0, stream>>>(qhb, khb, Vtb, aob);

    oproj_kernel<<<256, 256, 0, stream>>>(aob, Wob, bo, (float*)d_out);
}

// Round 5
// 137.083 us; speedup vs baseline: 1.1895x; 1.0384x over previous
//
#include <hip/hip_runtime.h>
#include <stdint.h>

// Problem constants
#define B_  2
#define S_  2048
#define D_  1024
#define H_  16
#define DK_ 64

typedef unsigned short u16;
typedef __attribute__((ext_vector_type(8))) __bf16 bf16x8;
typedef __attribute__((ext_vector_type(4))) float f32x4;
typedef __attribute__((ext_vector_type(4))) short short4v;
typedef __attribute__((ext_vector_type(8))) short short8v;

// f32 -> bf16 round-to-nearest-even (scalar, epilogue use)
static __device__ __forceinline__ u16 f2bf(float f) {
    union { float f; uint32_t u; } v; v.f = f;
    return (u16)((v.u + 0x7fffu + ((v.u >> 16) & 1u)) >> 16);
}
static __device__ __forceinline__ uint32_t pk2bf(float x, float y) {
    return (uint32_t)f2bf(x) | ((uint32_t)f2bf(y) << 16);
}
// HW packed f32x2 -> bf16x2 (RNE) — 1 VALU op (T12 primitive)
static __device__ __forceinline__ uint32_t cvtpk_bf16(float lo, float hi) {
    uint32_t r; asm("v_cvt_pk_bf16_f32 %0, %1, %2" : "=v"(r) : "v"(lo), "v"(hi));
    return r;
}
// raw 2^x
static __device__ __forceinline__ float exp2f_fast(float x) {
    float r; asm("v_exp_f32 %0, %1" : "=v"(r) : "v"(x)); return r;
}

// async global->LDS, 16B per lane. LDS dest = wave-uniform base + lane*16.
#define GLOAD16(gp, lp) \
    __builtin_amdgcn_global_load_lds((const __attribute__((address_space(1))) void*)(gp), \
                                     (__attribute__((address_space(3))) void*)(lp), 16, 0, 0)

// Universal LDS 16B-slot swizzle: phys = lin ^ ((lin>>3)&7). Involution.
static __device__ __forceinline__ int swz(int lin) { return lin ^ ((lin >> 3) & 7); }

// XCD-aware bijective block swizzle (nwg % 8 == 0): physical bid -> logical.
// Consecutive logical ids land on the SAME XCD (chunks of cpx = nwg/8).
static __device__ __forceinline__ int xcd_swz(int bid, int cpx) {
    return (bid & 7) * cpx + (bid >> 3);
}

// ------------------------------------------------------------- fused cast
__global__ __launch_bounds__(256) void cast_all_kernel(
        const float* __restrict__ q, const float* __restrict__ k, const float* __restrict__ v,
        const float* __restrict__ Wq, const float* __restrict__ Wk,
        const float* __restrict__ Wv, const float* __restrict__ Wo,
        u16* __restrict__ qb, u16* __restrict__ kb, u16* __restrict__ vb,
        u16* __restrict__ Wqb, u16* __restrict__ Wkb, u16* __restrict__ Wvb,
        u16* __restrict__ Wob) {
    int blk = blockIdx.x;
    const float* src; u16* dst; int off;
    if (blk < 2048)      { src = q;  dst = qb;  off = blk; }
    else if (blk < 4096) { src = k;  dst = kb;  off = blk - 2048; }
    else if (blk < 6144) { src = v;  dst = vb;  off = blk - 4096; }
    else if (blk < 6656) { src = Wq; dst = Wqb; off = blk - 6144; }
    else if (blk < 7168) { src = Wk; dst = Wkb; off = blk - 6656; }
    else if (blk < 7680) { src = Wv; dst = Wvb; off = blk - 7168; }
    else                 { src = Wo; dst = Wob; off = blk - 7680; }
    int i = (off * 256 + threadIdx.x) * 8;
    float4 a = *(const float4*)(src + i);
    float4 b = *(const float4*)(src + i + 4);
    uint4 r;
    r.x = pk2bf(a.x, a.y); r.y = pk2bf(a.z, a.w);
    r.z = pk2bf(b.x, b.y); r.w = pk2bf(b.z, b.w);
    *(uint4*)(void*)(dst + i) = r;
}

// ---------------------- 128x128 GEMM tile, 3-buffer counted-vmcnt pipeline
// C[m][n] = sum_k X[m][k]*W[n][k]. BK=32, 4 waves (2x2), 16 MFMA/wave/K-step.
// lds: 48KB = As[3][4096] @0, Bs[3][4096] @12288.
// Per iter: compute(kt) | barrier | stage(kt+2) | vmcnt(4) | barrier | SGB(0).
// stage(kt+2) stays in flight across the barrier (T4 counted-vmcnt).
__device__ __forceinline__ void gemm128_compute(
        const u16* __restrict__ X, const u16* __restrict__ W,
        int m0, int n0, u16* lds, f32x4 acc[4][4]) {
    const int tid = threadIdx.x, lane = tid & 63, w = tid >> 6;
    const int wm = w >> 1, wn = w & 1;
    u16* As = lds;
    u16* Bs = lds + 12288;

    auto stage = [&](int bi, int kt) {
#pragma unroll
        for (int r = 0; r < 2; ++r) {
            int s = tid + (r << 8);
            int lin = s ^ ((s >> 3) & 7);       // inverse swizzle (involution)
            int row = lin >> 2, ch = lin & 3;   // 64B rows: 4 chunks of 16B
            GLOAD16(X + (size_t)(m0 + row) * 1024 + (kt << 5) + (ch << 3),
                    (char*)(As + bi * 4096) + ((r << 8) + (w << 6)) * 16);
            GLOAD16(W + (size_t)(n0 + row) * 1024 + (kt << 5) + (ch << 3),
                    (char*)(Bs + bi * 4096) + ((r << 8) + (w << 6)) * 16);
        }
    };

    stage(0, 0);
    stage(1, 1);
    asm volatile("s_waitcnt vmcnt(4)" ::: "memory");   // stage(0) landed (mine)
    __builtin_amdgcn_s_barrier();                       // everyone's stage(0) landed
    __builtin_amdgcn_sched_barrier(0);

    int cur = 0, nxt2 = 2;
#pragma unroll 1
    for (int kt = 0; kt < 32; ++kt) {
        const char* Ab = (const char*)(As + cur * 4096);
        const char* Bb = (const char*)(Bs + cur * 4096);
        bf16x8 a[4], b[4];
#pragma unroll
        for (int f = 0; f < 4; ++f) {
            int rowa = wm * 64 + f * 16 + (lane & 15);
            a[f] = *(const bf16x8*)(Ab + swz(rowa * 4 + (lane >> 4)) * 16);
            int rowb = wn * 64 + f * 16 + (lane & 15);
            b[f] = *(const bf16x8*)(Bb + swz(rowb * 4 + (lane >> 4)) * 16);
        }
#pragma unroll
        for (int fm = 0; fm < 4; ++fm)
#pragma unroll
            for (int fn = 0; fn < 4; ++fn)
                acc[fm][fn] = __builtin_amdgcn_mfma_f32_16x16x32_bf16(
                    a[fm], b[fn], acc[fm][fn], 0, 0, 0);

        if (kt < 31) {
            __builtin_amdgcn_s_barrier();   // all waves done reading buf cur
            if (kt < 30) {
                stage(nxt2, kt + 2);        // overwrite buf read at kt-1 (safe)
                asm volatile("s_waitcnt vmcnt(4)" ::: "memory"); // stage(kt+1) landed
            } else {
                asm volatile("s_waitcnt vmcnt(0)" ::: "memory"); // stage(31) landed
            }
            __builtin_amdgcn_s_barrier();   // everyone's stage(kt+1) landed
            __builtin_amdgcn_sched_barrier(0);
        }
        cur = (cur == 2) ? 0 : cur + 1;
        nxt2 = (nxt2 == 2) ? 0 : nxt2 + 1;
    }
}

// QKV projection fused over flattened grid (768 blocks, XCD-swizzled).
// Q/K -> [B,H,S,DK] (Q pre-scaled by log2(e)/sqrt(DK)). V -> [BH,DK,S] via LDS.
__global__ __launch_bounds__(256) void qkv_proj_kernel(
        const u16* __restrict__ qX, const u16* __restrict__ kX, const u16* __restrict__ vX,
        const u16* __restrict__ Wq, const u16* __restrict__ Wk, const u16* __restrict__ Wv,
        const float* __restrict__ bq, const float* __restrict__ bk, const float* __restrict__ bv,
        u16* __restrict__ qo, u16* __restrict__ ko, u16* __restrict__ vt) {
    __shared__ __align__(16) u16 lds[24576];   // 48KB
    const int lg = xcd_swz(blockIdx.x, 96);    // 768 = 8 * 96
    const int which = lg >> 8;
    const int bid = lg & 255;
    const u16* X = which == 0 ? qX : (which == 1 ? kX : vX);
    const u16* W = which == 0 ? Wq : (which == 1 ? Wk : Wv);
    const float* bias = which == 0 ? bq : (which == 1 ? bk : bv);

    const int m0 = (bid >> 3) << 7;   // m-major: X-panel locality per XCD
    const int n0 = (bid & 7) << 7;
    f32x4 acc[4][4] = {};
    gemm128_compute(X, W, m0, n0, lds, acc);

    const int tid = threadIdx.x, lane = tid & 63, w = tid >> 6;
    const int wm = w >> 1, wn = w & 1;

    if (which < 2) {
        u16* out = which == 0 ? qo : ko;
        const float scale = which == 0 ? 0.1803368801111883f : 1.0f; // (1/8)*log2(e)
#pragma unroll
        for (int fn = 0; fn < 4; ++fn) {
            int n = n0 + wn * 64 + fn * 16 + (lane & 15);
            float bb = bias[n];
            int h = n >> 6, dk = n & 63;
#pragma unroll
            for (int fm = 0; fm < 4; ++fm)
#pragma unroll
                for (int j = 0; j < 4; ++j) {
                    int m = m0 + wm * 64 + fm * 16 + (lane >> 4) * 4 + j;
                    int b = m >> 11, s = m & 2047;
                    out[((size_t)(b * H_ + h) * S_ + s) * DK_ + dk] =
                        f2bf((acc[fm][fn][j] + bb) * scale);
                }
        }
    } else {
        // V: per 64-col half (= one head), transpose [128 s][64 dk] -> [64 dk][128 s]
        const int b = m0 >> 11, sbase = m0 & 2047;
        for (int nh = 0; nh < 2; ++nh) {
            __syncthreads();
            if (wn == nh) {
#pragma unroll
                for (int fn = 0; fn < 4; ++fn) {
                    int np = fn * 16 + (lane & 15);          // dk within head
                    float bb = bias[n0 + nh * 64 + np];
#pragma unroll
                    for (int fm = 0; fm < 4; ++fm) {
                        int mp0 = wm * 64 + fm * 16 + (lane >> 4) * 4;  // s within tile
                        short4v p;
#pragma unroll
                        for (int j = 0; j < 4; ++j)
                            p[j] = (short)f2bf(acc[fm][fn][j] + bb);
                        *(short4v*)(void*)&lds[np * 136 + mp0] = p;
                    }
                }
            }
            __syncthreads();
            int dk = tid >> 2, t4 = tid & 3;
            int h = (n0 >> 6) + nh;
            u16* dst = vt + ((size_t)((b * H_ + h) * DK_ + dk)) * S_ + sbase;
#pragma unroll
            for (int c = 0; c < 4; ++c) {
                int so = t4 * 8 + c * 32;
                *(short8v*)(void*)(dst + so) =
                    *(const short8v*)(const void*)&lds[dk * 136 + so];
            }
        }
    }
}

// Output projection: bf16 attn-out @ Wo^T + bo -> fp32 d_out
__global__ __launch_bounds__(256) void oproj_kernel(
        const u16* __restrict__ X, const u16* __restrict__ W,
        const float* __restrict__ bias, float* __restrict__ out) {
    __shared__ __align__(16) u16 lds[24576];   // 48KB
    const int bid = xcd_swz(blockIdx.x, 32);   // 256 = 8 * 32
    const int m0 = (bid >> 3) << 7;
    const int n0 = (bid & 7) << 7;
    f32x4 acc[4][4] = {};
    gemm128_compute(X, W, m0, n0, lds, acc);

    const int lane = threadIdx.x & 63, w = threadIdx.x >> 6;
    const int wm = w >> 1, wn = w & 1;
#pragma unroll
    for (int fn = 0; fn < 4; ++fn) {
        int n = n0 + wn * 64 + fn * 16 + (lane & 15);
        float bb = bias[n];
#pragma unroll
        for (int fm = 0; fm < 4; ++fm)
#pragma unroll
            for (int j = 0; j < 4; ++j) {
                int m = m0 + wm * 64 + fm * 16 + (lane >> 4) * 4 + j;
                out[(size_t)m * 1024 + n] = acc[fm][fn][j] + bb;
            }
    }
}

// ------------------------------------------------------------ flash attention
// Per block: one (b,h), 128 q-rows, 4 waves x 32 rows. KV tiles of 64.
// XCD-swizzled so all 16 q-tiles of one (b,h) share an XCD's L2 for K/V.
__global__ __launch_bounds__(256) void attn_kernel(
        const u16* __restrict__ qh, const u16* __restrict__ kh,
        const u16* __restrict__ Vt, u16* __restrict__ ao) {
    __shared__ __align__(16) u16 Qs[8192];       // 16KB
    __shared__ __align__(16) u16 Ks[2][4096];    // 16KB dbuf
    __shared__ __align__(16) u16 Vs[2][4096];    // 16KB dbuf
    __shared__ __align__(16) u16 Ps[8192];       // 16KB, per-wave 2048

    const int tid = threadIdx.x, lane = tid & 63, w = tid >> 6;
    const int lg = xcd_swz(blockIdx.x, 64);      // 512 = 8 * 64
    const int bh = lg >> 4, qt = lg & 15;
    const u16* qg = qh + ((size_t)bh * S_ + qt * 128) * DK_;
    const u16* kg = kh + (size_t)bh * S_ * DK_;
    const u16* vg = Vt + (size_t)bh * DK_ * S_;

    auto stageKV = [&](int bi, int kt) {
#pragma unroll
        for (int r = 0; r < 2; ++r) {
            int s = tid + (r << 8);
            int lin = s ^ ((s >> 3) & 7);
            int row = lin >> 3, ch = lin & 7;    // 128B rows: 8 chunks
            GLOAD16(kg + (size_t)(kt * 64 + row) * 64 + (ch << 3),
                    (char*)(&Ks[bi][0]) + ((r << 8) + (w << 6)) * 16);
            GLOAD16(vg + (size_t)row * S_ + kt * 64 + (ch << 3),
                    (char*)(&Vs[bi][0]) + ((r << 8) + (w << 6)) * 16);
        }
    };

    // prologue: stage Q tile + KV tile 0
#pragma unroll
    for (int r = 0; r < 4; ++r) {
        int s = tid + (r << 8);
        int lin = s ^ ((s >> 3) & 7);
        int row = lin >> 3, ch = lin & 7;
        GLOAD16(qg + row * 64 + (ch << 3), (char*)Qs + ((r << 8) + (w << 6)) * 16);
    }
    stageKV(0, 0);
    asm volatile("s_waitcnt vmcnt(0)" ::: "memory");
    __syncthreads();

    // Q fragments (B-operand): qrow = w*32+fn*16+(l&15)
    bf16x8 qf[2][2];
#pragma unroll
    for (int fn = 0; fn < 2; ++fn)
#pragma unroll
        for (int ks = 0; ks < 2; ++ks) {
            int row = w * 32 + fn * 16 + (lane & 15);
            qf[fn][ks] = *(const bf16x8*)((const char*)Qs +
                          swz(row * 8 + ks * 4 + (lane >> 4)) * 16);
        }

    // all-ones bf16 B-operand for the row-sum MFMA
    union { short8v s; bf16x8 b; } onesu;
#pragma unroll
    for (int i = 0; i < 8; ++i) onesu.s[i] = 0x3F80;
    const bf16x8 onesf = onesu.b;

    f32x4 acc[2][4] = {};
    f32x4 accl[2] = {};          // row-sum accumulator, same D-layout rows as acc
    u16* Pw = Ps + w * 2048;

#pragma unroll 1
    for (int kt = 0; kt < 32; ++kt) {
        const int cur = kt & 1;
        if (kt < 31) stageKV(cur ^ 1, kt + 1);   // prefetch next KV tile
        const char* Kb = (const char*)&Ks[cur][0];
        const char* Vb = (const char*)&Vs[cur][0];

        // St = K . Q^T
        f32x4 st[4][2] = {};
#pragma unroll
        for (int ks = 0; ks < 2; ++ks) {
            bf16x8 kf[4];
#pragma unroll
            for (int fm = 0; fm < 4; ++fm) {
                int row = fm * 16 + (lane & 15);
                kf[fm] = *(const bf16x8*)(Kb + swz(row * 8 + ks * 4 + (lane >> 4)) * 16);
            }
            __builtin_amdgcn_s_setprio(1);
#pragma unroll
            for (int fm = 0; fm < 4; ++fm)
#pragma unroll
                for (int fn = 0; fn < 2; ++fn)
                    st[fm][fn] = __builtin_amdgcn_mfma_f32_16x16x32_bf16(
                        kf[fm], qf[fn][ks], st[fm][fn], 0, 0, 0);
            __builtin_amdgcn_s_setprio(0);
        }

        // softmax numerator (exp2) + P pack via v_cvt_pk_bf16_f32
#pragma unroll
        for (int fm = 0; fm < 4; ++fm)
#pragma unroll
            for (int fn = 0; fn < 2; ++fn) {
                float e0 = exp2f_fast(st[fm][fn][0]);
                float e1 = exp2f_fast(st[fm][fn][1]);
                float e2 = exp2f_fast(st[fm][fn][2]);
                float e3 = exp2f_fast(st[fm][fn][3]);
                uint2 pk; pk.x = cvtpk_bf16(e0, e1); pk.y = cvtpk_bf16(e2, e3);
                int qrow = fn * 16 + (lane & 15);
                int g = lane >> 4;
                int slot = qrow * 8 + fm * 2 + (g >> 1);
                int ph = slot ^ (qrow & 7);
                *(uint2*)((char*)Pw + ph * 16 + (g & 1) * 8) = pk;
            }

        // PV: acc += P . V ; accl += P . 1 (row-sum on the MFMA pipe)
#pragma unroll
        for (int ks2 = 0; ks2 < 2; ++ks2) {
            bf16x8 pa[2], vb2[4];
#pragma unroll
            for (int fm2 = 0; fm2 < 2; ++fm2) {
                int row = fm2 * 16 + (lane & 15);
                pa[fm2] = *(const bf16x8*)((const char*)Pw +
                            swz(row * 8 + ks2 * 4 + (lane >> 4)) * 16);
            }
#pragma unroll
            for (int fn2 = 0; fn2 < 4; ++fn2) {
                int row = fn2 * 16 + (lane & 15);
                vb2[fn2] = *(const bf16x8*)(Vb + swz(row * 8 + ks2 * 4 + (lane >> 4)) * 16);
            }
            __builtin_amdgcn_s_setprio(1);
#pragma unroll
            for (int fm2 = 0; fm2 < 2; ++fm2) {
#pragma unroll
                for (int fn2 = 0; fn2 < 4; ++fn2)
                    acc[fm2][fn2] = __builtin_amdgcn_mfma_f32_16x16x32_bf16(
                        pa[fm2], vb2[fn2], acc[fm2][fn2], 0, 0, 0);
                accl[fm2] = __builtin_amdgcn_mfma_f32_16x16x32_bf16(
                    pa[fm2], onesf, accl[fm2], 0, 0, 0);
            }
            __builtin_amdgcn_s_setprio(0);
        }
        __syncthreads();   // drains prefetch vmcnt + lgkm, guards dbuf reuse
    }

    // epilogue: divide by row-sum (already in matching row layout), store bf16
    const int b = bh >> 4, h = bh & 15;
#pragma unroll
    for (int fm2 = 0; fm2 < 2; ++fm2) {
        float inv[4];
#pragma unroll
        for (int j = 0; j < 4; ++j)
            inv[j] = 1.0f / accl[fm2][j];
#pragma unroll
        for (int fn2 = 0; fn2 < 4; ++fn2)
#pragma unroll
            for (int j = 0; j < 4; ++j) {
                int srow = qt * 128 + w * 32 + fm2 * 16 + (lane >> 4) * 4 + j;
                int col = h * 64 + fn2 * 16 + (lane & 15);
                ao[((size_t)b * S_ + srow) * D_ + col] = f2bf(acc[fm2][fn2][j] * inv[j]);
            }
    }
}

// ---------------------------------------------------------------- launch
extern "C" void kernel_launch(void* const* d_in, const int* in_sizes, int n_in,
                              void* d_out, int out_size, void* d_ws, size_t ws_size,
                              hipStream_t stream) {
    const float* q  = (const float*)d_in[0];
    const float* k  = (const float*)d_in[1];
    const float* v  = (const float*)d_in[2];
    const float* Wq = (const float*)d_in[3];
    const float* bq = (const float*)d_in[4];
    const float* Wk = (const float*)d_in[5];
    const float* bk = (const float*)d_in[6];
    const float* Wv = (const float*)d_in[7];
    const float* bv = (const float*)d_in[8];
    const float* Wo = (const float*)d_in[9];
    const float* bo = (const float*)d_in[10];

    char* ws = (char*)d_ws;
    u16* qb  = (u16*)(ws);                  // 8 MiB
    u16* kb  = (u16*)(ws + (8u  << 20));    // 8 MiB (reused as attn-out)
    u16* vb  = (u16*)(ws + (16u << 20));    // 8 MiB
    u16* Wqb = (u16*)(ws + (24u << 20));    // 2 MiB each
    u16* Wkb = (u16*)(ws + (26u << 20));
    u16* Wvb = (u16*)(ws + (28u << 20));
    u16* Wob = (u16*)(ws + (30u << 20));
    u16* qhb = (u16*)(ws + (32u << 20));    // 8 MiB [B,H,S,DK]
    u16* khb = (u16*)(ws + (40u << 20));    // 8 MiB [B,H,S,DK]
    u16* Vtb = (u16*)(ws + (48u << 20));    // 8 MiB [BH,DK,S]
    u16* aob = kb;                          // alias: kb dead after qkv_proj

    cast_all_kernel<<<8192, 256, 0, stream>>>(q, k, v, Wq, Wk, Wv, Wo,
                                              qb, kb, vb, Wqb, Wkb, Wvb, Wob);

    qkv_proj_kernel<<<768, 256, 0, stream>>>(
        qb, kb, vb, Wqb, Wkb, Wvb, bq, bk, bv, qhb, khb, Vtb);

    attn_kernel<<<512, 256, 0, stream>>>(qhb, khb, Vtb, aob);

    oproj_kernel<<<256, 256, 0, stream>>>(aob, Wob, bo, (float*)d_out);
}

// Round 7
// 120.088 us; speedup vs baseline: 1.3578x; 1.1415x over previous
//
#include <hip/hip_runtime.h>
#include <stdint.h>

// Problem constants
#define B_  2
#define S_  2048
#define D_  1024
#define H_  16
#define DK_ 64

typedef unsigned short u16;
typedef __attribute__((ext_vector_type(8))) __bf16 bf16x8;
typedef __attribute__((ext_vector_type(4))) float f32x4;
typedef __attribute__((ext_vector_type(4))) short short4v;
typedef __attribute__((ext_vector_type(8))) short short8v;

// f32 -> bf16 round-to-nearest-even (scalar, epilogue use)
static __device__ __forceinline__ u16 f2bf(float f) {
    union { float f; uint32_t u; } v; v.f = f;
    return (u16)((v.u + 0x7fffu + ((v.u >> 16) & 1u)) >> 16);
}
static __device__ __forceinline__ uint32_t pk2bf(float x, float y) {
    return (uint32_t)f2bf(x) | ((uint32_t)f2bf(y) << 16);
}
// HW packed f32x2 -> bf16x2 (RNE) — 1 VALU op (T12 primitive)
static __device__ __forceinline__ uint32_t cvtpk_bf16(float lo, float hi) {
    uint32_t r; asm("v_cvt_pk_bf16_f32 %0, %1, %2" : "=v"(r) : "v"(lo), "v"(hi));
    return r;
}
// raw 2^x
static __device__ __forceinline__ float exp2f_fast(float x) {
    float r; asm("v_exp_f32 %0, %1" : "=v"(r) : "v"(x)); return r;
}

// async global->LDS, 16B per lane. LDS dest = wave-uniform base + lane*16.
#define GLOAD16(gp, lp) \
    __builtin_amdgcn_global_load_lds((const __attribute__((address_space(1))) void*)(gp), \
                                     (__attribute__((address_space(3))) void*)(lp), 16, 0, 0)

// Universal LDS 16B-slot swizzle: phys = lin ^ ((lin>>3)&7). Involution.
static __device__ __forceinline__ int swz(int lin) { return lin ^ ((lin >> 3) & 7); }

// XCD-aware bijective block swizzle (nwg % 8 == 0): physical bid -> logical.
static __device__ __forceinline__ int xcd_swz(int bid, int cpx) {
    return (bid & 7) * cpx + (bid >> 3);
}

// ------------------------------------------------------------- fused cast
__global__ __launch_bounds__(256) void cast_all_kernel(
        const float* __restrict__ q, const float* __restrict__ k, const float* __restrict__ v,
        const float* __restrict__ Wq, const float* __restrict__ Wk,
        const float* __restrict__ Wv, const float* __restrict__ Wo,
        u16* __restrict__ qb, u16* __restrict__ kb, u16* __restrict__ vb,
        u16* __restrict__ Wqb, u16* __restrict__ Wkb, u16* __restrict__ Wvb,
        u16* __restrict__ Wob) {
    int blk = blockIdx.x;
    const float* src; u16* dst; int off;
    if (blk < 2048)      { src = q;  dst = qb;  off = blk; }
    else if (blk < 4096) { src = k;  dst = kb;  off = blk - 2048; }
    else if (blk < 6144) { src = v;  dst = vb;  off = blk - 4096; }
    else if (blk < 6656) { src = Wq; dst = Wqb; off = blk - 6144; }
    else if (blk < 7168) { src = Wk; dst = Wkb; off = blk - 6656; }
    else if (blk < 7680) { src = Wv; dst = Wvb; off = blk - 7168; }
    else                 { src = Wo; dst = Wob; off = blk - 7680; }
    int i = (off * 256 + threadIdx.x) * 8;
    float4 a = *(const float4*)(src + i);
    float4 b = *(const float4*)(src + i + 4);
    uint4 r;
    r.x = pk2bf(a.x, a.y); r.y = pk2bf(a.z, a.w);
    r.z = pk2bf(b.x, b.y); r.w = pk2bf(b.z, b.w);
    *(uint4*)(void*)(dst + i) = r;
}

// ---------------------- 128x128 GEMM tile (oproj), 2-phase dbuf (unchanged)
__device__ __forceinline__ void gemm128_compute(
        const u16* __restrict__ X, const u16* __restrict__ W,
        int m0, int n0, u16* lds, f32x4 acc[4][4]) {
    const int tid = threadIdx.x, lane = tid & 63, w = tid >> 6;
    const int wm = w >> 1, wn = w & 1;
    u16* As = lds;
    u16* Bs = lds + 8192;

    auto stage = [&](int bi, int kt) {
#pragma unroll
        for (int r = 0; r < 2; ++r) {
            int s = tid + (r << 8);
            int lin = s ^ ((s >> 3) & 7);
            int row = lin >> 2, ch = lin & 3;
            GLOAD16(X + (size_t)(m0 + row) * 1024 + (kt << 5) + (ch << 3),
                    (char*)(As + bi * 4096) + ((r << 8) + (w << 6)) * 16);
            GLOAD16(W + (size_t)(n0 + row) * 1024 + (kt << 5) + (ch << 3),
                    (char*)(Bs + bi * 4096) + ((r << 8) + (w << 6)) * 16);
        }
    };

    stage(0, 0);
    asm volatile("s_waitcnt vmcnt(0)" ::: "memory");
    __syncthreads();
#pragma unroll 1
    for (int kt = 0; kt < 32; ++kt) {
        const int cur = kt & 1;
        if (kt < 31) stage(cur ^ 1, kt + 1);
        const char* Ab = (const char*)(As + cur * 4096);
        const char* Bb = (const char*)(Bs + cur * 4096);
        bf16x8 a[4], b[4];
#pragma unroll
        for (int f = 0; f < 4; ++f) {
            int rowa = wm * 64 + f * 16 + (lane & 15);
            a[f] = *(const bf16x8*)(Ab + swz(rowa * 4 + (lane >> 4)) * 16);
            int rowb = wn * 64 + f * 16 + (lane & 15);
            b[f] = *(const bf16x8*)(Bb + swz(rowb * 4 + (lane >> 4)) * 16);
        }
#pragma unroll
        for (int fm = 0; fm < 4; ++fm)
#pragma unroll
            for (int fn = 0; fn < 4; ++fn)
                acc[fm][fn] = __builtin_amdgcn_mfma_f32_16x16x32_bf16(
                    a[fm], b[fn], acc[fm][fn], 0, 0, 0);
        __syncthreads();
    }
}

// ---------------------------------------------------------------------------
// QKV projection: 256x256 tile, BK=64, 8 waves (2Mx4N), 8-phase schedule.
// Grid: 192 blocks x 512 thr (3 GEMMs x 16m x 4n tiles), XCD-swizzled.
// LDS 128KB: A[2 dbuf][2 half][128r][64c] bf16 @0, B same @32768 (u16 idx).
// Per iter (2 K-tiles t0,t1): phases p1..p8, per phase:
//   {ds-read subtile | stage 1 half-tile | (vmcnt@p4,p8) | bar | MFMA x16 | bar}
// Stage schedule: p1/p2: A(t1); p3/p4: B(t0+2); p5/p6: A(t0+2); p7/p8: B(t1+2).
// Every staged region's readers completed >=2 barriers earlier (audited).
// vmcnt(4) = 2 half-tiles (2 loads/thread each) left in flight.
// ---------------------------------------------------------------------------
__device__ __forceinline__ void stage_half(const u16* __restrict__ src,
        int R0, int kt, u16* dst, int tid) {
#pragma unroll
    for (int r = 0; r < 2; ++r) {
        int s = tid + (r << 9);                 // 512 threads, 1024 slots
        int lin = s ^ ((s >> 3) & 7);           // inverse swizzle (involution)
        int row = lin >> 3, ch = lin & 7;       // 128B rows: 8 chunks of 16B
        GLOAD16(src + (size_t)(R0 + row) * 1024 + (kt << 6) + (ch << 3),
                (char*)dst + ((r << 9) + ((tid >> 6) << 6)) * 16);
    }
}

#define VM4  asm volatile("s_waitcnt vmcnt(4)" ::: "memory")
#define VM0  asm volatile("s_waitcnt vmcnt(0)" ::: "memory")

#define PHASE(QQ, MP, LOADB, STAGE_STMT, VM_STMT)                                \
    {                                                                            \
        bf16x8 afr[2][2];                                                        \
        if (LOADB) {                                                             \
            _Pragma("unroll") for (int fn = 0; fn < 4; ++fn)                     \
            _Pragma("unroll") for (int ks = 0; ks < 2; ++ks) {                   \
                int lin = (brow0 + fn * 16 + (lane & 15)) * 8 + ks * 4 + (lane >> 4); \
                bfr[fn][ks] = *(const bf16x8*)(Bhb[QQ] + swz(lin) * 16);         \
            }                                                                    \
        }                                                                        \
        _Pragma("unroll") for (int fo = 0; fo < 2; ++fo)                         \
        _Pragma("unroll") for (int ks = 0; ks < 2; ++ks) {                       \
            int lin = ((MP) * 32 + fo * 16 + (lane & 15)) * 8 + ks * 4 + (lane >> 4); \
            afr[fo][ks] = *(const bf16x8*)(Ahb[QQ] + swz(lin) * 16);             \
        }                                                                        \
        STAGE_STMT;                                                              \
        VM_STMT;                                                                 \
        __builtin_amdgcn_s_barrier();                                            \
        __builtin_amdgcn_sched_barrier(0);                                       \
        __builtin_amdgcn_s_setprio(1);                                           \
        _Pragma("unroll") for (int fo = 0; fo < 2; ++fo)                         \
        _Pragma("unroll") for (int ks = 0; ks < 2; ++ks)                         \
        _Pragma("unroll") for (int fn = 0; fn < 4; ++fn)                         \
            acc[(MP) * 2 + fo][fn] = __builtin_amdgcn_mfma_f32_16x16x32_bf16(    \
                afr[fo][ks], bfr[fn][ks], acc[(MP) * 2 + fo][fn], 0, 0, 0);      \
        __builtin_amdgcn_s_setprio(0);                                           \
        __builtin_amdgcn_s_barrier();                                            \
        __builtin_amdgcn_sched_barrier(0);                                       \
    }

__global__ __launch_bounds__(512, 2) void qkv256_kernel(
        const u16* __restrict__ qX, const u16* __restrict__ kX, const u16* __restrict__ vX,
        const u16* __restrict__ Wq, const u16* __restrict__ Wk, const u16* __restrict__ Wv,
        const float* __restrict__ bq, const float* __restrict__ bk, const float* __restrict__ bv,
        u16* __restrict__ qo, u16* __restrict__ ko, u16* __restrict__ vt) {
    __shared__ __align__(16) u16 lds[65536];    // 128 KB
    const int tid = threadIdx.x, lane = tid & 63, w = tid >> 6;
    const int wm = w >> 2, wn = w & 3;          // 2 x 4 waves
    const int lg = xcd_swz(blockIdx.x, 24);     // 192 = 8 * 24
    const int which = lg >> 6;                  // 0=Q 1=K 2=V
    const int rem = lg & 63;
    const int n0 = (rem >> 4) << 8;             // 4 n-tiles
    const int m0 = (rem & 15) << 8;             // 16 m-tiles (m-minor: share W panel)
    const u16* X = which == 0 ? qX : (which == 1 ? kX : vX);
    const u16* W = which == 0 ? Wq : (which == 1 ? Wk : Wv);
    const float* bias = which == 0 ? bq : (which == 1 ? bk : bv);

    u16* Abase = lds;              // [dbuf][half][1024 slots]
    u16* Bbase = lds + 32768;

    // prologue: tile0 {A0,A1,B0,B1}; tile1 {B0,B1}
    stage_half(X, m0,        0, Abase + 0,             tid);
    stage_half(X, m0 + 128,  0, Abase + 8192,          tid);
    stage_half(W, n0,        0, Bbase + 0,             tid);
    stage_half(W, n0 + 128,  0, Bbase + 8192,          tid);
    stage_half(W, n0,        1, Bbase + 16384,         tid);
    stage_half(W, n0 + 128,  1, Bbase + 16384 + 8192,  tid);
    VM4;                                         // tile0's 4 halves landed
    __builtin_amdgcn_s_barrier();
    __builtin_amdgcn_sched_barrier(0);

    f32x4 acc[8][4] = {};
    bf16x8 bfr[4][2];
    const char* Ahb[2] = { (const char*)(Abase + wm * 8192),
                           (const char*)(Abase + 16384 + wm * 8192) };
    const char* Bhb[2] = { (const char*)(Bbase + (wn >> 1) * 8192),
                           (const char*)(Bbase + 16384 + (wn >> 1) * 8192) };
    const int brow0 = (wn & 1) * 64;

#pragma unroll 1
    for (int i = 0; i < 8; ++i) {
        const int t0 = 2 * i, t1 = 2 * i + 1;
        const bool nl = (i < 7);                 // not-last
        // p1..p4: compute t0 (buf 0)
        PHASE(0, 0, true,  stage_half(X, m0,       t1,     Abase + 16384,        tid), (void)0);
        PHASE(0, 1, false, stage_half(X, m0 + 128, t1,     Abase + 16384 + 8192, tid), (void)0);
        PHASE(0, 2, false, if (nl) stage_half(W, n0,       t0 + 2, Bbase + 0,    tid), (void)0);
        PHASE(0, 3, false, if (nl) stage_half(W, n0 + 128, t0 + 2, Bbase + 8192, tid),
              if (nl) { VM4; } else { VM0; });
        // p5..p8: compute t1 (buf 1)
        PHASE(1, 0, true,  if (nl) stage_half(X, m0,       t0 + 2, Abase + 0,    tid), (void)0);
        PHASE(1, 1, false, if (nl) stage_half(X, m0 + 128, t0 + 2, Abase + 8192, tid), (void)0);
        PHASE(1, 2, false, if (nl) stage_half(W, n0,       t1 + 2, Bbase + 16384, tid), (void)0);
        PHASE(1, 3, false, if (nl) stage_half(W, n0 + 128, t1 + 2, Bbase + 16384 + 8192, tid),
              if (nl) { VM4; });
    }

    // ---------------- epilogues
    if (which < 2) {
        u16* out = which == 0 ? qo : ko;
        const float scale = which == 0 ? 0.1803368801111883f : 1.0f; // (1/8)*log2(e)
#pragma unroll
        for (int fn = 0; fn < 4; ++fn) {
            int n = n0 + wn * 64 + fn * 16 + (lane & 15);
            float bb = bias[n];
            int h = n >> 6, dk = n & 63;
#pragma unroll
            for (int fm = 0; fm < 8; ++fm)
#pragma unroll
                for (int j = 0; j < 4; ++j) {
                    int m = m0 + wm * 128 + fm * 16 + (lane >> 4) * 4 + j;
                    int b = m >> 11, s = m & 2047;
                    out[((size_t)(b * H_ + h) * S_ + s) * DK_ + dk] =
                        f2bf((acc[fm][fn][j] + bb) * scale);
                }
        }
    } else {
        // V: per-wave private 16KB LDS transpose [128 s][64 dk] -> [64 dk][128 s]
        __syncthreads();                         // all compute LDS reads done
        u16* wl = lds + w * 8192;
#pragma unroll
        for (int fn = 0; fn < 4; ++fn) {
            int dk = fn * 16 + (lane & 15);
            float bb = bias[n0 + wn * 64 + dk];
            int xr = (dk & 7) << 3;
#pragma unroll
            for (int fm = 0; fm < 8; ++fm) {
                int sl = fm * 16 + (lane >> 4) * 4;
                short4v p;
#pragma unroll
                for (int j = 0; j < 4; ++j) p[j] = (short)f2bf(acc[fm][fn][j] + bb);
                *(short4v*)(void*)&wl[dk * 128 + (sl ^ xr)] = p;
            }
        }
        int mrow = m0 + wm * 128;
        int b = mrow >> 11, sbase = mrow & 2047;
        int h = (n0 >> 6) + wn;
        u16* dst = vt + ((size_t)(b * H_ + h) * DK_) * S_ + sbase;
#pragma unroll
        for (int oc = 0; oc < 8; ++oc)
#pragma unroll
            for (int ic = 0; ic < 2; ++ic) {
                int dk = oc * 8 + (lane >> 3);
                int sc = ic * 8 + (lane & 7);
                short8v vv = *(const short8v*)(const void*)
                    &wl[dk * 128 + ((sc * 8) ^ ((dk & 7) << 3))];
                *(short8v*)(void*)(dst + (size_t)dk * S_ + sc * 8) = vv;
            }
    }
}

// Output projection: bf16 attn-out @ Wo^T + bo -> fp32 d_out (unchanged)
__global__ __launch_bounds__(256) void oproj_kernel(
        const u16* __restrict__ X, const u16* __restrict__ W,
        const float* __restrict__ bias, float* __restrict__ out) {
    __shared__ __align__(16) u16 lds[16384];
    const int bid = xcd_swz(blockIdx.x, 32);
    const int m0 = (bid >> 3) << 7;
    const int n0 = (bid & 7) << 7;
    f32x4 acc[4][4] = {};
    gemm128_compute(X, W, m0, n0, lds, acc);

    const int lane = threadIdx.x & 63, w = threadIdx.x >> 6;
    const int wm = w >> 1, wn = w & 1;
#pragma unroll
    for (int fn = 0; fn < 4; ++fn) {
        int n = n0 + wn * 64 + fn * 16 + (lane & 15);
        float bb = bias[n];
#pragma unroll
        for (int fm = 0; fm < 4; ++fm)
#pragma unroll
            for (int j = 0; j < 4; ++j) {
                int m = m0 + wm * 64 + fm * 16 + (lane >> 4) * 4 + j;
                out[(size_t)m * 1024 + n] = acc[fm][fn][j] + bb;
            }
    }
}

// ------------------------------------------------------------ flash attention
// (unchanged from R4/R5 working version)
__global__ __launch_bounds__(256) void attn_kernel(
        const u16* __restrict__ qh, const u16* __restrict__ kh,
        const u16* __restrict__ Vt, u16* __restrict__ ao) {
    __shared__ __align__(16) u16 Qs[8192];
    __shared__ __align__(16) u16 Ks[2][4096];
    __shared__ __align__(16) u16 Vs[2][4096];
    __shared__ __align__(16) u16 Ps[8192];

    const int tid = threadIdx.x, lane = tid & 63, w = tid >> 6;
    const int lg = xcd_swz(blockIdx.x, 64);
    const int bh = lg >> 4, qt = lg & 15;
    const u16* qg = qh + ((size_t)bh * S_ + qt * 128) * DK_;
    const u16* kg = kh + (size_t)bh * S_ * DK_;
    const u16* vg = Vt + (size_t)bh * DK_ * S_;

    auto stageKV = [&](int bi, int kt) {
#pragma unroll
        for (int r = 0; r < 2; ++r) {
            int s = tid + (r << 8);
            int lin = s ^ ((s >> 3) & 7);
            int row = lin >> 3, ch = lin & 7;
            GLOAD16(kg + (size_t)(kt * 64 + row) * 64 + (ch << 3),
                    (char*)(&Ks[bi][0]) + ((r << 8) + (w << 6)) * 16);
            GLOAD16(vg + (size_t)row * S_ + kt * 64 + (ch << 3),
                    (char*)(&Vs[bi][0]) + ((r << 8) + (w << 6)) * 16);
        }
    };

#pragma unroll
    for (int r = 0; r < 4; ++r) {
        int s = tid + (r << 8);
        int lin = s ^ ((s >> 3) & 7);
        int row = lin >> 3, ch = lin & 7;
        GLOAD16(qg + row * 64 + (ch << 3), (char*)Qs + ((r << 8) + (w << 6)) * 16);
    }
    stageKV(0, 0);
    asm volatile("s_waitcnt vmcnt(0)" ::: "memory");
    __syncthreads();

    bf16x8 qf[2][2];
#pragma unroll
    for (int fn = 0; fn < 2; ++fn)
#pragma unroll
        for (int ks = 0; ks < 2; ++ks) {
            int row = w * 32 + fn * 16 + (lane & 15);
            qf[fn][ks] = *(const bf16x8*)((const char*)Qs +
                          swz(row * 8 + ks * 4 + (lane >> 4)) * 16);
        }

    union { short8v s; bf16x8 b; } onesu;
#pragma unroll
    for (int i = 0; i < 8; ++i) onesu.s[i] = 0x3F80;
    const bf16x8 onesf = onesu.b;

    f32x4 acc[2][4] = {};
    f32x4 accl[2] = {};
    u16* Pw = Ps + w * 2048;

#pragma unroll 1
    for (int kt = 0; kt < 32; ++kt) {
        const int cur = kt & 1;
        if (kt < 31) stageKV(cur ^ 1, kt + 1);
        const char* Kb = (const char*)&Ks[cur][0];
        const char* Vb = (const char*)&Vs[cur][0];

        f32x4 st[4][2] = {};
#pragma unroll
        for (int ks = 0; ks < 2; ++ks) {
            bf16x8 kf[4];
#pragma unroll
            for (int fm = 0; fm < 4; ++fm) {
                int row = fm * 16 + (lane & 15);
                kf[fm] = *(const bf16x8*)(Kb + swz(row * 8 + ks * 4 + (lane >> 4)) * 16);
            }
            __builtin_amdgcn_s_setprio(1);
#pragma unroll
            for (int fm = 0; fm < 4; ++fm)
#pragma unroll
                for (int fn = 0; fn < 2; ++fn)
                    st[fm][fn] = __builtin_amdgcn_mfma_f32_16x16x32_bf16(
                        kf[fm], qf[fn][ks], st[fm][fn], 0, 0, 0);
            __builtin_amdgcn_s_setprio(0);
        }

#pragma unroll
        for (int fm = 0; fm < 4; ++fm)
#pragma unroll
            for (int fn = 0; fn < 2; ++fn) {
                float e0 = exp2f_fast(st[fm][fn][0]);
                float e1 = exp2f_fast(st[fm][fn][1]);
                float e2 = exp2f_fast(st[fm][fn][2]);
                float e3 = exp2f_fast(st[fm][fn][3]);
                uint2 pk; pk.x = cvtpk_bf16(e0, e1); pk.y = cvtpk_bf16(e2, e3);
                int qrow = fn * 16 + (lane & 15);
                int g = lane >> 4;
                int slot = qrow * 8 + fm * 2 + (g >> 1);
                int ph = slot ^ (qrow & 7);
                *(uint2*)((char*)Pw + ph * 16 + (g & 1) * 8) = pk;
            }

#pragma unroll
        for (int ks2 = 0; ks2 < 2; ++ks2) {
            bf16x8 pa[2], vb2[4];
#pragma unroll
            for (int fm2 = 0; fm2 < 2; ++fm2) {
                int row = fm2 * 16 + (lane & 15);
                pa[fm2] = *(const bf16x8*)((const char*)Pw +
                            swz(row * 8 + ks2 * 4 + (lane >> 4)) * 16);
            }
#pragma unroll
            for (int fn2 = 0; fn2 < 4; ++fn2) {
                int row = fn2 * 16 + (lane & 15);
                vb2[fn2] = *(const bf16x8*)(Vb + swz(row * 8 + ks2 * 4 + (lane >> 4)) * 16);
            }
            __builtin_amdgcn_s_setprio(1);
#pragma unroll
            for (int fm2 = 0; fm2 < 2; ++fm2) {
#pragma unroll
                for (int fn2 = 0; fn2 < 4; ++fn2)
                    acc[fm2][fn2] = __builtin_amdgcn_mfma_f32_16x16x32_bf16(
                        pa[fm2], vb2[fn2], acc[fm2][fn2], 0, 0, 0);
                accl[fm2] = __builtin_amdgcn_mfma_f32_16x16x32_bf16(
                    pa[fm2], onesf, accl[fm2], 0, 0, 0);
            }
            __builtin_amdgcn_s_setprio(0);
        }
        __syncthreads();
    }

    const int b = bh >> 4, h = bh & 15;
#pragma unroll
    for (int fm2 = 0; fm2 < 2; ++fm2) {
        float inv[4];
#pragma unroll
        for (int j = 0; j < 4; ++j)
            inv[j] = 1.0f / accl[fm2][j];
#pragma unroll
        for (int fn2 = 0; fn2 < 4; ++fn2)
#pragma unroll
            for (int j = 0; j < 4; ++j) {
                int srow = qt * 128 + w * 32 + fm2 * 16 + (lane >> 4) * 4 + j;
                int col = h * 64 + fn2 * 16 + (lane & 15);
                ao[((size_t)b * S_ + srow) * D_ + col] = f2bf(acc[fm2][fn2][j] * inv[j]);
            }
    }
}

// ---------------------------------------------------------------- launch
extern "C" void kernel_launch(void* const* d_in, const int* in_sizes, int n_in,
                              void* d_out, int out_size, void* d_ws, size_t ws_size,
                              hipStream_t stream) {
    const float* q  = (const float*)d_in[0];
    const float* k  = (const float*)d_in[1];
    const float* v  = (const float*)d_in[2];
    const float* Wq = (const float*)d_in[3];
    const float* bq = (const float*)d_in[4];
    const float* Wk = (const float*)d_in[5];
    const float* bk = (const float*)d_in[6];
    const float* Wv = (const float*)d_in[7];
    const float* bv = (const float*)d_in[8];
    const float* Wo = (const float*)d_in[9];
    const float* bo = (const float*)d_in[10];

    char* ws = (char*)d_ws;
    u16* qb  = (u16*)(ws);                  // 8 MiB
    u16* kb  = (u16*)(ws + (8u  << 20));    // 8 MiB (reused as attn-out)
    u16* vb  = (u16*)(ws + (16u << 20));    // 8 MiB
    u16* Wqb = (u16*)(ws + (24u << 20));    // 2 MiB each
    u16* Wkb = (u16*)(ws + (26u << 20));
    u16* Wvb = (u16*)(ws + (28u << 20));
    u16* Wob = (u16*)(ws + (30u << 20));
    u16* qhb = (u16*)(ws + (32u << 20));    // 8 MiB [B,H,S,DK]
    u16* khb = (u16*)(ws + (40u << 20));    // 8 MiB [B,H,S,DK]
    u16* Vtb = (u16*)(ws + (48u << 20));    // 8 MiB [BH,DK,S]
    u16* aob = kb;                          // alias: kb dead after qkv

    cast_all_kernel<<<8192, 256, 0, stream>>>(q, k, v, Wq, Wk, Wv, Wo,
                                              qb, kb, vb, Wqb, Wkb, Wvb, Wob);

    qkv256_kernel<<<192, 512, 0, stream>>>(
        qb, kb, vb, Wqb, Wkb, Wvb, bq, bk, bv, qhb, khb, Vtb);

    attn_kernel<<<512, 256, 0, stream>>>(qhb, khb, Vtb, aob);

    oproj_kernel<<<256, 256, 0, stream>>>(aob, Wob, bo, (float*)d_out);
}

// Round 8
// 117.141 us; speedup vs baseline: 1.3920x; 1.0252x over previous
//
#include <hip/hip_runtime.h>
#include <stdint.h>

// Problem constants
#define B_  2
#define S_  2048
#define D_  1024
#define H_  16
#define DK_ 64

typedef unsigned short u16;
typedef __attribute__((ext_vector_type(8))) __bf16 bf16x8;
typedef __attribute__((ext_vector_type(4))) float f32x4;
typedef __attribute__((ext_vector_type(16))) float f32x16;
typedef __attribute__((ext_vector_type(4))) short short4v;
typedef __attribute__((ext_vector_type(8))) short short8v;

// f32 -> bf16 round-to-nearest-even (scalar, epilogue use)
static __device__ __forceinline__ u16 f2bf(float f) {
    union { float f; uint32_t u; } v; v.f = f;
    return (u16)((v.u + 0x7fffu + ((v.u >> 16) & 1u)) >> 16);
}
static __device__ __forceinline__ uint32_t pk2bf(float x, float y) {
    return (uint32_t)f2bf(x) | ((uint32_t)f2bf(y) << 16);
}
// HW packed f32x2 -> bf16x2 (RNE) — 1 VALU op (T12 primitive)
static __device__ __forceinline__ uint32_t cvtpk_bf16(float lo, float hi) {
    uint32_t r; asm("v_cvt_pk_bf16_f32 %0, %1, %2" : "=v"(r) : "v"(lo), "v"(hi));
    return r;
}
// raw 2^x
static __device__ __forceinline__ float exp2f_fast(float x) {
    float r; asm("v_exp_f32 %0, %1" : "=v"(r) : "v"(x)); return r;
}

// async global->LDS, 16B per lane. LDS dest = wave-uniform base + lane*16.
#define GLOAD16(gp, lp) \
    __builtin_amdgcn_global_load_lds((const __attribute__((address_space(1))) void*)(gp), \
                                     (__attribute__((address_space(3))) void*)(lp), 16, 0, 0)

// Universal LDS 16B-slot swizzle: phys = lin ^ ((lin>>3)&7). Involution.
static __device__ __forceinline__ int swz(int lin) { return lin ^ ((lin >> 3) & 7); }

// XCD-aware bijective block swizzle (nwg % 8 == 0): physical bid -> logical.
static __device__ __forceinline__ int xcd_swz(int bid, int cpx) {
    return (bid & 7) * cpx + (bid >> 3);
}

// ------------------------------------------------------------- fused cast
__global__ __launch_bounds__(256) void cast_all_kernel(
        const float* __restrict__ q, const float* __restrict__ k, const float* __restrict__ v,
        const float* __restrict__ Wq, const float* __restrict__ Wk,
        const float* __restrict__ Wv, const float* __restrict__ Wo,
        u16* __restrict__ qb, u16* __restrict__ kb, u16* __restrict__ vb,
        u16* __restrict__ Wqb, u16* __restrict__ Wkb, u16* __restrict__ Wvb,
        u16* __restrict__ Wob) {
    int blk = blockIdx.x;
    const float* src; u16* dst; int off;
    if (blk < 2048)      { src = q;  dst = qb;  off = blk; }
    else if (blk < 4096) { src = k;  dst = kb;  off = blk - 2048; }
    else if (blk < 6144) { src = v;  dst = vb;  off = blk - 4096; }
    else if (blk < 6656) { src = Wq; dst = Wqb; off = blk - 6144; }
    else if (blk < 7168) { src = Wk; dst = Wkb; off = blk - 6656; }
    else if (blk < 7680) { src = Wv; dst = Wvb; off = blk - 7168; }
    else                 { src = Wo; dst = Wob; off = blk - 7680; }
    int i = (off * 256 + threadIdx.x) * 8;
    float4 a = *(const float4*)(src + i);
    float4 b = *(const float4*)(src + i + 4);
    uint4 r;
    r.x = pk2bf(a.x, a.y); r.y = pk2bf(a.z, a.w);
    r.z = pk2bf(b.x, b.y); r.w = pk2bf(b.z, b.w);
    *(uint4*)(void*)(dst + i) = r;
}

// ---------------------- 128x128 GEMM tile (oproj), 2-phase dbuf (unchanged)
__device__ __forceinline__ void gemm128_compute(
        const u16* __restrict__ X, const u16* __restrict__ W,
        int m0, int n0, u16* lds, f32x4 acc[4][4]) {
    const int tid = threadIdx.x, lane = tid & 63, w = tid >> 6;
    const int wm = w >> 1, wn = w & 1;
    u16* As = lds;
    u16* Bs = lds + 8192;

    auto stage = [&](int bi, int kt) {
#pragma unroll
        for (int r = 0; r < 2; ++r) {
            int s = tid + (r << 8);
            int lin = s ^ ((s >> 3) & 7);
            int row = lin >> 2, ch = lin & 3;
            GLOAD16(X + (size_t)(m0 + row) * 1024 + (kt << 5) + (ch << 3),
                    (char*)(As + bi * 4096) + ((r << 8) + (w << 6)) * 16);
            GLOAD16(W + (size_t)(n0 + row) * 1024 + (kt << 5) + (ch << 3),
                    (char*)(Bs + bi * 4096) + ((r << 8) + (w << 6)) * 16);
        }
    };

    stage(0, 0);
    asm volatile("s_waitcnt vmcnt(0)" ::: "memory");
    __syncthreads();
#pragma unroll 1
    for (int kt = 0; kt < 32; ++kt) {
        const int cur = kt & 1;
        if (kt < 31) stage(cur ^ 1, kt + 1);
        const char* Ab = (const char*)(As + cur * 4096);
        const char* Bb = (const char*)(Bs + cur * 4096);
        bf16x8 a[4], b[4];
#pragma unroll
        for (int f = 0; f < 4; ++f) {
            int rowa = wm * 64 + f * 16 + (lane & 15);
            a[f] = *(const bf16x8*)(Ab + swz(rowa * 4 + (lane >> 4)) * 16);
            int rowb = wn * 64 + f * 16 + (lane & 15);
            b[f] = *(const bf16x8*)(Bb + swz(rowb * 4 + (lane >> 4)) * 16);
        }
#pragma unroll
        for (int fm = 0; fm < 4; ++fm)
#pragma unroll
            for (int fn = 0; fn < 4; ++fn)
                acc[fm][fn] = __builtin_amdgcn_mfma_f32_16x16x32_bf16(
                    a[fm], b[fn], acc[fm][fn], 0, 0, 0);
        __syncthreads();
    }
}

// ---------------------------------------------------------------------------
// QKV projection: 256x256 tile, BK=64, 8 waves (2Mx4N), 8-phase schedule.
// (unchanged from R7 working version)
// ---------------------------------------------------------------------------
__device__ __forceinline__ void stage_half(const u16* __restrict__ src,
        int R0, int kt, u16* dst, int tid) {
#pragma unroll
    for (int r = 0; r < 2; ++r) {
        int s = tid + (r << 9);                 // 512 threads, 1024 slots
        int lin = s ^ ((s >> 3) & 7);           // inverse swizzle (involution)
        int row = lin >> 3, ch = lin & 7;       // 128B rows: 8 chunks of 16B
        GLOAD16(src + (size_t)(R0 + row) * 1024 + (kt << 6) + (ch << 3),
                (char*)dst + ((r << 9) + ((tid >> 6) << 6)) * 16);
    }
}

#define VM4  asm volatile("s_waitcnt vmcnt(4)" ::: "memory")
#define VM0  asm volatile("s_waitcnt vmcnt(0)" ::: "memory")

#define PHASE(QQ, MP, LOADB, STAGE_STMT, VM_STMT)                                \
    {                                                                            \
        bf16x8 afr[2][2];                                                        \
        if (LOADB) {                                                             \
            _Pragma("unroll") for (int fn = 0; fn < 4; ++fn)                     \
            _Pragma("unroll") for (int ks = 0; ks < 2; ++ks) {                   \
                int lin = (brow0 + fn * 16 + (lane & 15)) * 8 + ks * 4 + (lane >> 4); \
                bfr[fn][ks] = *(const bf16x8*)(Bhb[QQ] + swz(lin) * 16);         \
            }                                                                    \
        }                                                                        \
        _Pragma("unroll") for (int fo = 0; fo < 2; ++fo)                         \
        _Pragma("unroll") for (int ks = 0; ks < 2; ++ks) {                       \
            int lin = ((MP) * 32 + fo * 16 + (lane & 15)) * 8 + ks * 4 + (lane >> 4); \
            afr[fo][ks] = *(const bf16x8*)(Ahb[QQ] + swz(lin) * 16);             \
        }                                                                        \
        STAGE_STMT;                                                              \
        VM_STMT;                                                                 \
        __builtin_amdgcn_s_barrier();                                            \
        __builtin_amdgcn_sched_barrier(0);                                       \
        __builtin_amdgcn_s_setprio(1);                                           \
        _Pragma("unroll") for (int fo = 0; fo < 2; ++fo)                         \
        _Pragma("unroll") for (int ks = 0; ks < 2; ++ks)                         \
        _Pragma("unroll") for (int fn = 0; fn < 4; ++fn)                         \
            acc[(MP) * 2 + fo][fn] = __builtin_amdgcn_mfma_f32_16x16x32_bf16(    \
                afr[fo][ks], bfr[fn][ks], acc[(MP) * 2 + fo][fn], 0, 0, 0);      \
        __builtin_amdgcn_s_setprio(0);                                           \
        __builtin_amdgcn_s_barrier();                                            \
        __builtin_amdgcn_sched_barrier(0);                                       \
    }

__global__ __launch_bounds__(512, 2) void qkv256_kernel(
        const u16* __restrict__ qX, const u16* __restrict__ kX, const u16* __restrict__ vX,
        const u16* __restrict__ Wq, const u16* __restrict__ Wk, const u16* __restrict__ Wv,
        const float* __restrict__ bq, const float* __restrict__ bk, const float* __restrict__ bv,
        u16* __restrict__ qo, u16* __restrict__ ko, u16* __restrict__ vt) {
    __shared__ __align__(16) u16 lds[65536];    // 128 KB
    const int tid = threadIdx.x, lane = tid & 63, w = tid >> 6;
    const int wm = w >> 2, wn = w & 3;          // 2 x 4 waves
    const int lg = xcd_swz(blockIdx.x, 24);     // 192 = 8 * 24
    const int which = lg >> 6;                  // 0=Q 1=K 2=V
    const int rem = lg & 63;
    const int n0 = (rem >> 4) << 8;             // 4 n-tiles
    const int m0 = (rem & 15) << 8;             // 16 m-tiles (m-minor: share W panel)
    const u16* X = which == 0 ? qX : (which == 1 ? kX : vX);
    const u16* W = which == 0 ? Wq : (which == 1 ? Wk : Wv);
    const float* bias = which == 0 ? bq : (which == 1 ? bk : bv);

    u16* Abase = lds;              // [dbuf][half][1024 slots]
    u16* Bbase = lds + 32768;

    // prologue: tile0 {A0,A1,B0,B1}; tile1 {B0,B1}
    stage_half(X, m0,        0, Abase + 0,             tid);
    stage_half(X, m0 + 128,  0, Abase + 8192,          tid);
    stage_half(W, n0,        0, Bbase + 0,             tid);
    stage_half(W, n0 + 128,  0, Bbase + 8192,          tid);
    stage_half(W, n0,        1, Bbase + 16384,         tid);
    stage_half(W, n0 + 128,  1, Bbase + 16384 + 8192,  tid);
    VM4;                                         // tile0's 4 halves landed
    __builtin_amdgcn_s_barrier();
    __builtin_amdgcn_sched_barrier(0);

    f32x4 acc[8][4] = {};
    bf16x8 bfr[4][2];
    const char* Ahb[2] = { (const char*)(Abase + wm * 8192),
                           (const char*)(Abase + 16384 + wm * 8192) };
    const char* Bhb[2] = { (const char*)(Bbase + (wn >> 1) * 8192),
                           (const char*)(Bbase + 16384 + (wn >> 1) * 8192) };
    const int brow0 = (wn & 1) * 64;

#pragma unroll 1
    for (int i = 0; i < 8; ++i) {
        const int t0 = 2 * i, t1 = 2 * i + 1;
        const bool nl = (i < 7);                 // not-last
        // p1..p4: compute t0 (buf 0)
        PHASE(0, 0, true,  stage_half(X, m0,       t1,     Abase + 16384,        tid), (void)0);
        PHASE(0, 1, false, stage_half(X, m0 + 128, t1,     Abase + 16384 + 8192, tid), (void)0);
        PHASE(0, 2, false, if (nl) stage_half(W, n0,       t0 + 2, Bbase + 0,    tid), (void)0);
        PHASE(0, 3, false, if (nl) stage_half(W, n0 + 128, t0 + 2, Bbase + 8192, tid),
              if (nl) { VM4; } else { VM0; });
        // p5..p8: compute t1 (buf 1)
        PHASE(1, 0, true,  if (nl) stage_half(X, m0,       t0 + 2, Abase + 0,    tid), (void)0);
        PHASE(1, 1, false, if (nl) stage_half(X, m0 + 128, t0 + 2, Abase + 8192, tid), (void)0);
        PHASE(1, 2, false, if (nl) stage_half(W, n0,       t1 + 2, Bbase + 16384, tid), (void)0);
        PHASE(1, 3, false, if (nl) stage_half(W, n0 + 128, t1 + 2, Bbase + 16384 + 8192, tid),
              if (nl) { VM4; });
    }

    // ---------------- epilogues
    if (which < 2) {
        u16* out = which == 0 ? qo : ko;
        const float scale = which == 0 ? 0.1803368801111883f : 1.0f; // (1/8)*log2(e)
#pragma unroll
        for (int fn = 0; fn < 4; ++fn) {
            int n = n0 + wn * 64 + fn * 16 + (lane & 15);
            float bb = bias[n];
            int h = n >> 6, dk = n & 63;
#pragma unroll
            for (int fm = 0; fm < 8; ++fm)
#pragma unroll
                for (int j = 0; j < 4; ++j) {
                    int m = m0 + wm * 128 + fm * 16 + (lane >> 4) * 4 + j;
                    int b = m >> 11, s = m & 2047;
                    out[((size_t)(b * H_ + h) * S_ + s) * DK_ + dk] =
                        f2bf((acc[fm][fn][j] + bb) * scale);
                }
        }
    } else {
        // V: per-wave private 16KB LDS transpose [128 s][64 dk] -> [64 dk][128 s]
        __syncthreads();                         // all compute LDS reads done
        u16* wl = lds + w * 8192;
#pragma unroll
        for (int fn = 0; fn < 4; ++fn) {
            int dk = fn * 16 + (lane & 15);
            float bb = bias[n0 + wn * 64 + dk];
            int xr = (dk & 7) << 3;
#pragma unroll
            for (int fm = 0; fm < 8; ++fm) {
                int sl = fm * 16 + (lane >> 4) * 4;
                short4v p;
#pragma unroll
                for (int j = 0; j < 4; ++j) p[j] = (short)f2bf(acc[fm][fn][j] + bb);
                *(short4v*)(void*)&wl[dk * 128 + (sl ^ xr)] = p;
            }
        }
        int mrow = m0 + wm * 128;
        int b = mrow >> 11, sbase = mrow & 2047;
        int h = (n0 >> 6) + wn;
        u16* dst = vt + ((size_t)(b * H_ + h) * DK_) * S_ + sbase;
#pragma unroll
        for (int oc = 0; oc < 8; ++oc)
#pragma unroll
            for (int ic = 0; ic < 2; ++ic) {
                int dk = oc * 8 + (lane >> 3);
                int sc = ic * 8 + (lane & 7);
                short8v vv = *(const short8v*)(const void*)
                    &wl[dk * 128 + ((sc * 8) ^ ((dk & 7) << 3))];
                *(short8v*)(void*)(dst + (size_t)dk * S_ + sc * 8) = vv;
            }
    }
}

// Output projection: bf16 attn-out @ Wo^T + bo -> fp32 d_out (unchanged)
__global__ __launch_bounds__(256) void oproj_kernel(
        const u16* __restrict__ X, const u16* __restrict__ W,
        const float* __restrict__ bias, float* __restrict__ out) {
    __shared__ __align__(16) u16 lds[16384];
    const int bid = xcd_swz(blockIdx.x, 32);
    const int m0 = (bid >> 3) << 7;
    const int n0 = (bid & 7) << 7;
    f32x4 acc[4][4] = {};
    gemm128_compute(X, W, m0, n0, lds, acc);

    const int lane = threadIdx.x & 63, w = threadIdx.x >> 6;
    const int wm = w >> 1, wn = w & 1;
#pragma unroll
    for (int fn = 0; fn < 4; ++fn) {
        int n = n0 + wn * 64 + fn * 16 + (lane & 15);
        float bb = bias[n];
#pragma unroll
        for (int fm = 0; fm < 4; ++fm)
#pragma unroll
            for (int j = 0; j < 4; ++j) {
                int m = m0 + wm * 64 + fm * 16 + (lane >> 4) * 4 + j;
                out[(size_t)m * 1024 + n] = acc[fm][fn][j] + bb;
            }
    }
}

// ------------------------------------------------------------ flash attention
// 32x32x16 MFMA version. Per block: one (b,h), 128 q-rows, 4 waves x 32 rows.
// KV tiles of 64. Swapped QK^T: st = mfma32(K, Q): D[col=lane&31=qrow]
// [row=(reg&3)+8*(reg>>2)+4*(lane>>5)=key]. P converted to the PV A-operand
// IN REGISTERS via 16 cvt_pk + 8 v_permlane32_swap per kt (T12) — no P LDS.
// Row-sum via mfma32(pa, ones) -> same reg layout as acc (trivial epilogue).
__global__ __launch_bounds__(256, 2) void attn_kernel(
        const u16* __restrict__ qh, const u16* __restrict__ kh,
        const u16* __restrict__ Vt, u16* __restrict__ ao) {
    __shared__ __align__(16) u16 Qs[8192];       // 16KB  [128 q][64 dk]
    __shared__ __align__(16) u16 Ks[2][4096];    // 16KB dbuf [64 key][64 dk]
    __shared__ __align__(16) u16 Vs[2][4096];    // 16KB dbuf [64 dk][64 key]

    const int tid = threadIdx.x, lane = tid & 63, w = tid >> 6;
    const int l31 = lane & 31, hh = lane >> 5;   // half-wave index
    const int lg = xcd_swz(blockIdx.x, 64);      // 512 = 8 * 64
    const int bh = lg >> 4, qt = lg & 15;
    const u16* qg = qh + ((size_t)bh * S_ + qt * 128) * DK_;
    const u16* kg = kh + (size_t)bh * S_ * DK_;
    const u16* vg = Vt + (size_t)bh * DK_ * S_;

    auto stageKV = [&](int bi, int kt) {
#pragma unroll
        for (int r = 0; r < 2; ++r) {
            int s = tid + (r << 8);
            int lin = s ^ ((s >> 3) & 7);
            int row = lin >> 3, ch = lin & 7;
            GLOAD16(kg + (size_t)(kt * 64 + row) * 64 + (ch << 3),
                    (char*)(&Ks[bi][0]) + ((r << 8) + (w << 6)) * 16);
            GLOAD16(vg + (size_t)row * S_ + kt * 64 + (ch << 3),
                    (char*)(&Vs[bi][0]) + ((r << 8) + (w << 6)) * 16);
        }
    };

    // prologue: stage Q tile + KV tile 0
#pragma unroll
    for (int r = 0; r < 4; ++r) {
        int s = tid + (r << 8);
        int lin = s ^ ((s >> 3) & 7);
        int row = lin >> 3, ch = lin & 7;
        GLOAD16(qg + row * 64 + (ch << 3), (char*)Qs + ((r << 8) + (w << 6)) * 16);
    }
    stageKV(0, 0);
    asm volatile("s_waitcnt vmcnt(0)" ::: "memory");
    __syncthreads();

    // Q fragments (B-operand, 32x32x16): lane holds col=qrow=l31, k-run
    // dk = c*16 + hh*8 .. +8.  4 chunks cover DK=64.
    bf16x8 qf[4];
#pragma unroll
    for (int c = 0; c < 4; ++c) {
        int row = w * 32 + l31;
        qf[c] = *(const bf16x8*)((const char*)Qs + swz(row * 8 + c * 2 + hh) * 16);
    }

    // all-ones bf16 B-operand for the row-sum MFMA
    union { short8v s; bf16x8 b; } onesu;
#pragma unroll
    for (int i = 0; i < 8; ++i) onesu.s[i] = 0x3F80;
    const bf16x8 onesf = onesu.b;

    f32x16 acc[2] = {};      // PV out: D[col=dk(l31)+nb*32][row=q reg-layout]
    f32x16 accl = {};        // row-sum, same reg layout

#pragma unroll 1
    for (int kt = 0; kt < 32; ++kt) {
        const int cur = kt & 1;
        if (kt < 31) stageKV(cur ^ 1, kt + 1);
        const char* Kb = (const char*)&Ks[cur][0];
        const char* Vb = (const char*)&Vs[cur][0];

        // QK^T: st[kb] = K[kb-block] . Q^T   (2 key-blocks x 4 k-chunks)
        f32x16 st[2] = {};
#pragma unroll
        for (int kb = 0; kb < 2; ++kb) {
            bf16x8 kf[4];
#pragma unroll
            for (int c = 0; c < 4; ++c) {
                int row = kb * 32 + l31;
                kf[c] = *(const bf16x8*)(Kb + swz(row * 8 + c * 2 + hh) * 16);
            }
            __builtin_amdgcn_s_setprio(1);
#pragma unroll
            for (int c = 0; c < 4; ++c)
                st[kb] = __builtin_amdgcn_mfma_f32_32x32x16_bf16(
                    kf[c], qf[c], st[kb], 0, 0, 0);
            __builtin_amdgcn_s_setprio(0);
        }

        // softmax numerator (exp2; scale folded into Q) + in-register repack:
        // chunk c (16 keys): regs o..o+7 of st[c>>1], o=(c&1)*8.
        // u0=cvtpk(e0,e1) u1=cvtpk(e2,e3) u2=cvtpk(e4,e5) u3=cvtpk(e6,e7);
        // permlane32_swap(u0,u2), (u1,u3) -> (u0,u1,u2,u3) = A-frag words.
        bf16x8 pa[4];
#pragma unroll
        for (int c = 0; c < 4; ++c) {
            const int kb = c >> 1, o = (c & 1) * 8;
            float e0 = exp2f_fast(st[kb][o + 0]);
            float e1 = exp2f_fast(st[kb][o + 1]);
            float e2 = exp2f_fast(st[kb][o + 2]);
            float e3 = exp2f_fast(st[kb][o + 3]);
            float e4 = exp2f_fast(st[kb][o + 4]);
            float e5 = exp2f_fast(st[kb][o + 5]);
            float e6 = exp2f_fast(st[kb][o + 6]);
            float e7 = exp2f_fast(st[kb][o + 7]);
            uint32_t u0 = cvtpk_bf16(e0, e1);
            uint32_t u1 = cvtpk_bf16(e2, e3);
            uint32_t u2 = cvtpk_bf16(e4, e5);
            uint32_t u3 = cvtpk_bf16(e6, e7);
            asm volatile("v_permlane32_swap_b32 %0, %1" : "+v"(u0), "+v"(u2));
            asm volatile("v_permlane32_swap_b32 %0, %1" : "+v"(u1), "+v"(u3));
            union { uint32_t u[4]; bf16x8 v; } pu;
            pu.u[0] = u0; pu.u[1] = u1; pu.u[2] = u2; pu.u[3] = u3;
            pa[c] = pu.v;
        }

        // row-sum on MFMA pipe + PV: acc[nb] += P . V
        __builtin_amdgcn_s_setprio(1);
#pragma unroll
        for (int c = 0; c < 4; ++c)
            accl = __builtin_amdgcn_mfma_f32_32x32x16_bf16(
                pa[c], onesf, accl, 0, 0, 0);
        __builtin_amdgcn_s_setprio(0);
#pragma unroll
        for (int nb = 0; nb < 2; ++nb) {
            bf16x8 vf[4];
#pragma unroll
            for (int c = 0; c < 4; ++c) {
                int row = nb * 32 + l31;
                vf[c] = *(const bf16x8*)(Vb + swz(row * 8 + c * 2 + hh) * 16);
            }
            __builtin_amdgcn_s_setprio(1);
#pragma unroll
            for (int c = 0; c < 4; ++c)
                acc[nb] = __builtin_amdgcn_mfma_f32_32x32x16_bf16(
                    pa[c], vf[c], acc[nb], 0, 0, 0);
            __builtin_amdgcn_s_setprio(0);
        }
        __syncthreads();   // drains prefetch vmcnt + lgkm, guards dbuf reuse
    }

    // epilogue: divide by row-sum (same reg layout), store bf16 [B,S,H*DK]
    const int bb = bh >> 4, hd = bh & 15;
#pragma unroll
    for (int r = 0; r < 16; ++r) {
        float inv = 1.0f / accl[r];
        int ql = (r & 3) + 8 * (r >> 2) + 4 * hh;
        int srow = qt * 128 + w * 32 + ql;
#pragma unroll
        for (int nb = 0; nb < 2; ++nb) {
            int col = hd * 64 + nb * 32 + l31;
            ao[((size_t)bb * S_ + srow) * D_ + col] = f2bf(acc[nb][r] * inv);
        }
    }
}

// ---------------------------------------------------------------- launch
extern "C" void kernel_launch(void* const* d_in, const int* in_sizes, int n_in,
                              void* d_out, int out_size, void* d_ws, size_t ws_size,
                              hipStream_t stream) {
    const float* q  = (const float*)d_in[0];
    const float* k  = (const float*)d_in[1];
    const float* v  = (const float*)d_in[2];
    const float* Wq = (const float*)d_in[3];
    const float* bq = (const float*)d_in[4];
    const float* Wk = (const float*)d_in[5];
    const float* bk = (const float*)d_in[6];
    const float* Wv = (const float*)d_in[7];
    const float* bv = (const float*)d_in[8];
    const float* Wo = (const float*)d_in[9];
    const float* bo = (const float*)d_in[10];

    char* ws = (char*)d_ws;
    u16* qb  = (u16*)(ws);                  // 8 MiB
    u16* kb  = (u16*)(ws + (8u  << 20));    // 8 MiB (reused as attn-out)
    u16* vb  = (u16*)(ws + (16u << 20));    // 8 MiB
    u16* Wqb = (u16*)(ws + (24u << 20));    // 2 MiB each
    u16* Wkb = (u16*)(ws + (26u << 20));
    u16* Wvb = (u16*)(ws + (28u << 20));
    u16* Wob = (u16*)(ws + (30u << 20));
    u16* qhb = (u16*)(ws + (32u << 20));    // 8 MiB [B,H,S,DK]
    u16* khb = (u16*)(ws + (40u << 20));    // 8 MiB [B,H,S,DK]
    u16* Vtb = (u16*)(ws + (48u << 20));    // 8 MiB [BH,DK,S]
    u16* aob = kb;                          // alias: kb dead after qkv

    cast_all_kernel<<<8192, 256, 0, stream>>>(q, k, v, Wq, Wk, Wv, Wo,
                                              qb, kb, vb, Wqb, Wkb, Wvb, Wob);

    qkv256_kernel<<<192, 512, 0, stream>>>(
        qb, kb, vb, Wqb, Wkb, Wvb, bq, bk, bv, qhb, khb, Vtb);

    attn_kernel<<<512, 256, 0, stream>>>(qhb, khb, Vtb, aob);

    oproj_kernel<<<256, 256, 0, stream>>>(aob, Wob, bo, (float*)d_out);
}

// Round 9
// 115.376 us; speedup vs baseline: 1.4133x; 1.0153x over previous
//
#include <hip/hip_runtime.h>
#include <stdint.h>

// Problem constants
#define B_  2
#define S_  2048
#define D_  1024
#define H_  16
#define DK_ 64

typedef unsigned short u16;
typedef __attribute__((ext_vector_type(8))) __bf16 bf16x8;
typedef __attribute__((ext_vector_type(4))) float f32x4;
typedef __attribute__((ext_vector_type(16))) float f32x16;
typedef __attribute__((ext_vector_type(4))) short short4v;
typedef __attribute__((ext_vector_type(8))) short short8v;

// f32 -> bf16 round-to-nearest-even (scalar, epilogue use)
static __device__ __forceinline__ u16 f2bf(float f) {
    union { float f; uint32_t u; } v; v.f = f;
    return (u16)((v.u + 0x7fffu + ((v.u >> 16) & 1u)) >> 16);
}
static __device__ __forceinline__ uint32_t pk2bf(float x, float y) {
    return (uint32_t)f2bf(x) | ((uint32_t)f2bf(y) << 16);
}
// HW packed f32x2 -> bf16x2 (RNE) — 1 VALU op (T12 primitive)
static __device__ __forceinline__ uint32_t cvtpk_bf16(float lo, float hi) {
    uint32_t r; asm("v_cvt_pk_bf16_f32 %0, %1, %2" : "=v"(r) : "v"(lo), "v"(hi));
    return r;
}
// raw 2^x
static __device__ __forceinline__ float exp2f_fast(float x) {
    float r; asm("v_exp_f32 %0, %1" : "=v"(r) : "v"(x)); return r;
}

// async global->LDS, 16B per lane. LDS dest = wave-uniform base + lane*16.
#define GLOAD16(gp, lp) \
    __builtin_amdgcn_global_load_lds((const __attribute__((address_space(1))) void*)(gp), \
                                     (__attribute__((address_space(3))) void*)(lp), 16, 0, 0)

// Universal LDS 16B-slot swizzle: phys = lin ^ ((lin>>3)&7). Involution.
static __device__ __forceinline__ int swz(int lin) { return lin ^ ((lin >> 3) & 7); }
// attn swizzle: also fold row bits 3-4 into the bank-group (involution:
// target bits 0-2, source bits 3-8 disjoint). Breaks the 4-way collisions
// of the 32x32 read pattern (lanes l, l+8, l+16, l+24 sharing a group).
static __device__ __forceinline__ int swz2(int lin) {
    return lin ^ ((lin >> 3) & 7) ^ ((lin >> 6) & 3);
}

// XCD-aware bijective block swizzle (nwg % 8 == 0): physical bid -> logical.
static __device__ __forceinline__ int xcd_swz(int bid, int cpx) {
    return (bid & 7) * cpx + (bid >> 3);
}

// ------------------------------------------------------------- fused cast
__global__ __launch_bounds__(256) void cast_all_kernel(
        const float* __restrict__ q, const float* __restrict__ k, const float* __restrict__ v,
        const float* __restrict__ Wq, const float* __restrict__ Wk,
        const float* __restrict__ Wv, const float* __restrict__ Wo,
        u16* __restrict__ qb, u16* __restrict__ kb, u16* __restrict__ vb,
        u16* __restrict__ Wqb, u16* __restrict__ Wkb, u16* __restrict__ Wvb,
        u16* __restrict__ Wob) {
    int blk = blockIdx.x;
    const float* src; u16* dst; int off;
    if (blk < 2048)      { src = q;  dst = qb;  off = blk; }
    else if (blk < 4096) { src = k;  dst = kb;  off = blk - 2048; }
    else if (blk < 6144) { src = v;  dst = vb;  off = blk - 4096; }
    else if (blk < 6656) { src = Wq; dst = Wqb; off = blk - 6144; }
    else if (blk < 7168) { src = Wk; dst = Wkb; off = blk - 6656; }
    else if (blk < 7680) { src = Wv; dst = Wvb; off = blk - 7168; }
    else                 { src = Wo; dst = Wob; off = blk - 7680; }
    int i = (off * 256 + threadIdx.x) * 8;
    float4 a = *(const float4*)(src + i);
    float4 b = *(const float4*)(src + i + 4);
    uint4 r;
    r.x = pk2bf(a.x, a.y); r.y = pk2bf(a.z, a.w);
    r.z = pk2bf(b.x, b.y); r.w = pk2bf(b.z, b.w);
    *(uint4*)(void*)(dst + i) = r;
}

// ---------------------- 128x128 GEMM tile (oproj), 2-phase dbuf (unchanged)
__device__ __forceinline__ void gemm128_compute(
        const u16* __restrict__ X, const u16* __restrict__ W,
        int m0, int n0, u16* lds, f32x4 acc[4][4]) {
    const int tid = threadIdx.x, lane = tid & 63, w = tid >> 6;
    const int wm = w >> 1, wn = w & 1;
    u16* As = lds;
    u16* Bs = lds + 8192;

    auto stage = [&](int bi, int kt) {
#pragma unroll
        for (int r = 0; r < 2; ++r) {
            int s = tid + (r << 8);
            int lin = s ^ ((s >> 3) & 7);
            int row = lin >> 2, ch = lin & 3;
            GLOAD16(X + (size_t)(m0 + row) * 1024 + (kt << 5) + (ch << 3),
                    (char*)(As + bi * 4096) + ((r << 8) + (w << 6)) * 16);
            GLOAD16(W + (size_t)(n0 + row) * 1024 + (kt << 5) + (ch << 3),
                    (char*)(Bs + bi * 4096) + ((r << 8) + (w << 6)) * 16);
        }
    };

    stage(0, 0);
    asm volatile("s_waitcnt vmcnt(0)" ::: "memory");
    __syncthreads();
#pragma unroll 1
    for (int kt = 0; kt < 32; ++kt) {
        const int cur = kt & 1;
        if (kt < 31) stage(cur ^ 1, kt + 1);
        const char* Ab = (const char*)(As + cur * 4096);
        const char* Bb = (const char*)(Bs + cur * 4096);
        bf16x8 a[4], b[4];
#pragma unroll
        for (int f = 0; f < 4; ++f) {
            int rowa = wm * 64 + f * 16 + (lane & 15);
            a[f] = *(const bf16x8*)(Ab + swz(rowa * 4 + (lane >> 4)) * 16);
            int rowb = wn * 64 + f * 16 + (lane & 15);
            b[f] = *(const bf16x8*)(Bb + swz(rowb * 4 + (lane >> 4)) * 16);
        }
#pragma unroll
        for (int fm = 0; fm < 4; ++fm)
#pragma unroll
            for (int fn = 0; fn < 4; ++fn)
                acc[fm][fn] = __builtin_amdgcn_mfma_f32_16x16x32_bf16(
                    a[fm], b[fn], acc[fm][fn], 0, 0, 0);
        __syncthreads();
    }
}

// ---------------------------------------------------------------------------
// QKV projection: 256x256 tile, BK=64, 8 waves (2Mx4N), 8-phase schedule.
// (unchanged from R7 working version)
// ---------------------------------------------------------------------------
__device__ __forceinline__ void stage_half(const u16* __restrict__ src,
        int R0, int kt, u16* dst, int tid) {
#pragma unroll
    for (int r = 0; r < 2; ++r) {
        int s = tid + (r << 9);                 // 512 threads, 1024 slots
        int lin = s ^ ((s >> 3) & 7);           // inverse swizzle (involution)
        int row = lin >> 3, ch = lin & 7;       // 128B rows: 8 chunks of 16B
        GLOAD16(src + (size_t)(R0 + row) * 1024 + (kt << 6) + (ch << 3),
                (char*)dst + ((r << 9) + ((tid >> 6) << 6)) * 16);
    }
}

#define VM4  asm volatile("s_waitcnt vmcnt(4)" ::: "memory")
#define VM0  asm volatile("s_waitcnt vmcnt(0)" ::: "memory")

#define PHASE(QQ, MP, LOADB, STAGE_STMT, VM_STMT)                                \
    {                                                                            \
        bf16x8 afr[2][2];                                                        \
        if (LOADB) {                                                             \
            _Pragma("unroll") for (int fn = 0; fn < 4; ++fn)                     \
            _Pragma("unroll") for (int ks = 0; ks < 2; ++ks) {                   \
                int lin = (brow0 + fn * 16 + (lane & 15)) * 8 + ks * 4 + (lane >> 4); \
                bfr[fn][ks] = *(const bf16x8*)(Bhb[QQ] + swz(lin) * 16);         \
            }                                                                    \
        }                                                                        \
        _Pragma("unroll") for (int fo = 0; fo < 2; ++fo)                         \
        _Pragma("unroll") for (int ks = 0; ks < 2; ++ks) {                       \
            int lin = ((MP) * 32 + fo * 16 + (lane & 15)) * 8 + ks * 4 + (lane >> 4); \
            afr[fo][ks] = *(const bf16x8*)(Ahb[QQ] + swz(lin) * 16);             \
        }                                                                        \
        STAGE_STMT;                                                              \
        VM_STMT;                                                                 \
        __builtin_amdgcn_s_barrier();                                            \
        __builtin_amdgcn_sched_barrier(0);                                       \
        __builtin_amdgcn_s_setprio(1);                                           \
        _Pragma("unroll") for (int fo = 0; fo < 2; ++fo)                         \
        _Pragma("unroll") for (int ks = 0; ks < 2; ++ks)                         \
        _Pragma("unroll") for (int fn = 0; fn < 4; ++fn)                         \
            acc[(MP) * 2 + fo][fn] = __builtin_amdgcn_mfma_f32_16x16x32_bf16(    \
                afr[fo][ks], bfr[fn][ks], acc[(MP) * 2 + fo][fn], 0, 0, 0);      \
        __builtin_amdgcn_s_setprio(0);                                           \
        __builtin_amdgcn_s_barrier();                                            \
        __builtin_amdgcn_sched_barrier(0);                                       \
    }

__global__ __launch_bounds__(512, 2) void qkv256_kernel(
        const u16* __restrict__ qX, const u16* __restrict__ kX, const u16* __restrict__ vX,
        const u16* __restrict__ Wq, const u16* __restrict__ Wk, const u16* __restrict__ Wv,
        const float* __restrict__ bq, const float* __restrict__ bk, const float* __restrict__ bv,
        u16* __restrict__ qo, u16* __restrict__ ko, u16* __restrict__ vt) {
    __shared__ __align__(16) u16 lds[65536];    // 128 KB
    const int tid = threadIdx.x, lane = tid & 63, w = tid >> 6;
    const int wm = w >> 2, wn = w & 3;          // 2 x 4 waves
    const int lg = xcd_swz(blockIdx.x, 24);     // 192 = 8 * 24
    const int which = lg >> 6;                  // 0=Q 1=K 2=V
    const int rem = lg & 63;
    const int n0 = (rem >> 4) << 8;             // 4 n-tiles
    const int m0 = (rem & 15) << 8;             // 16 m-tiles (m-minor: share W panel)
    const u16* X = which == 0 ? qX : (which == 1 ? kX : vX);
    const u16* W = which == 0 ? Wq : (which == 1 ? Wk : Wv);
    const float* bias = which == 0 ? bq : (which == 1 ? bk : bv);

    u16* Abase = lds;              // [dbuf][half][1024 slots]
    u16* Bbase = lds + 32768;

    // prologue: tile0 {A0,A1,B0,B1}; tile1 {B0,B1}
    stage_half(X, m0,        0, Abase + 0,             tid);
    stage_half(X, m0 + 128,  0, Abase + 8192,          tid);
    stage_half(W, n0,        0, Bbase + 0,             tid);
    stage_half(W, n0 + 128,  0, Bbase + 8192,          tid);
    stage_half(W, n0,        1, Bbase + 16384,         tid);
    stage_half(W, n0 + 128,  1, Bbase + 16384 + 8192,  tid);
    VM4;                                         // tile0's 4 halves landed
    __builtin_amdgcn_s_barrier();
    __builtin_amdgcn_sched_barrier(0);

    f32x4 acc[8][4] = {};
    bf16x8 bfr[4][2];
    const char* Ahb[2] = { (const char*)(Abase + wm * 8192),
                           (const char*)(Abase + 16384 + wm * 8192) };
    const char* Bhb[2] = { (const char*)(Bbase + (wn >> 1) * 8192),
                           (const char*)(Bbase + 16384 + (wn >> 1) * 8192) };
    const int brow0 = (wn & 1) * 64;

#pragma unroll 1
    for (int i = 0; i < 8; ++i) {
        const int t0 = 2 * i, t1 = 2 * i + 1;
        const bool nl = (i < 7);                 // not-last
        // p1..p4: compute t0 (buf 0)
        PHASE(0, 0, true,  stage_half(X, m0,       t1,     Abase + 16384,        tid), (void)0);
        PHASE(0, 1, false, stage_half(X, m0 + 128, t1,     Abase + 16384 + 8192, tid), (void)0);
        PHASE(0, 2, false, if (nl) stage_half(W, n0,       t0 + 2, Bbase + 0,    tid), (void)0);
        PHASE(0, 3, false, if (nl) stage_half(W, n0 + 128, t0 + 2, Bbase + 8192, tid),
              if (nl) { VM4; } else { VM0; });
        // p5..p8: compute t1 (buf 1)
        PHASE(1, 0, true,  if (nl) stage_half(X, m0,       t0 + 2, Abase + 0,    tid), (void)0);
        PHASE(1, 1, false, if (nl) stage_half(X, m0 + 128, t0 + 2, Abase + 8192, tid), (void)0);
        PHASE(1, 2, false, if (nl) stage_half(W, n0,       t1 + 2, Bbase + 16384, tid), (void)0);
        PHASE(1, 3, false, if (nl) stage_half(W, n0 + 128, t1 + 2, Bbase + 16384 + 8192, tid),
              if (nl) { VM4; });
    }

    // ---------------- epilogues
    if (which < 2) {
        u16* out = which == 0 ? qo : ko;
        const float scale = which == 0 ? 0.1803368801111883f : 1.0f; // (1/8)*log2(e)
#pragma unroll
        for (int fn = 0; fn < 4; ++fn) {
            int n = n0 + wn * 64 + fn * 16 + (lane & 15);
            float bb = bias[n];
            int h = n >> 6, dk = n & 63;
#pragma unroll
            for (int fm = 0; fm < 8; ++fm)
#pragma unroll
                for (int j = 0; j < 4; ++j) {
                    int m = m0 + wm * 128 + fm * 16 + (lane >> 4) * 4 + j;
                    int b = m >> 11, s = m & 2047;
                    out[((size_t)(b * H_ + h) * S_ + s) * DK_ + dk] =
                        f2bf((acc[fm][fn][j] + bb) * scale);
                }
        }
    } else {
        // V: per-wave private 16KB LDS transpose [128 s][64 dk] -> [64 dk][128 s]
        __syncthreads();                         // all compute LDS reads done
        u16* wl = lds + w * 8192;
#pragma unroll
        for (int fn = 0; fn < 4; ++fn) {
            int dk = fn * 16 + (lane & 15);
            float bb = bias[n0 + wn * 64 + dk];
            int xr = (dk & 7) << 3;
#pragma unroll
            for (int fm = 0; fm < 8; ++fm) {
                int sl = fm * 16 + (lane >> 4) * 4;
                short4v p;
#pragma unroll
                for (int j = 0; j < 4; ++j) p[j] = (short)f2bf(acc[fm][fn][j] + bb);
                *(short4v*)(void*)&wl[dk * 128 + (sl ^ xr)] = p;
            }
        }
        int mrow = m0 + wm * 128;
        int b = mrow >> 11, sbase = mrow & 2047;
        int h = (n0 >> 6) + wn;
        u16* dst = vt + ((size_t)(b * H_ + h) * DK_) * S_ + sbase;
#pragma unroll
        for (int oc = 0; oc < 8; ++oc)
#pragma unroll
            for (int ic = 0; ic < 2; ++ic) {
                int dk = oc * 8 + (lane >> 3);
                int sc = ic * 8 + (lane & 7);
                short8v vv = *(const short8v*)(const void*)
                    &wl[dk * 128 + ((sc * 8) ^ ((dk & 7) << 3))];
                *(short8v*)(void*)(dst + (size_t)dk * S_ + sc * 8) = vv;
            }
    }
}

// Output projection: bf16 attn-out @ Wo^T + bo -> fp32 d_out (unchanged)
__global__ __launch_bounds__(256) void oproj_kernel(
        const u16* __restrict__ X, const u16* __restrict__ W,
        const float* __restrict__ bias, float* __restrict__ out) {
    __shared__ __align__(16) u16 lds[16384];
    const int bid = xcd_swz(blockIdx.x, 32);
    const int m0 = (bid >> 3) << 7;
    const int n0 = (bid & 7) << 7;
    f32x4 acc[4][4] = {};
    gemm128_compute(X, W, m0, n0, lds, acc);

    const int lane = threadIdx.x & 63, w = threadIdx.x >> 6;
    const int wm = w >> 1, wn = w & 1;
#pragma unroll
    for (int fn = 0; fn < 4; ++fn) {
        int n = n0 + wn * 64 + fn * 16 + (lane & 15);
        float bb = bias[n];
#pragma unroll
        for (int fm = 0; fm < 4; ++fm)
#pragma unroll
            for (int j = 0; j < 4; ++j) {
                int m = m0 + wm * 64 + fm * 16 + (lane >> 4) * 4 + j;
                out[(size_t)m * 1024 + n] = acc[fm][fn][j] + bb;
            }
    }
}

// ------------------------------------------------------------ flash attention
// 32x32x16 MFMA, 2-tile iterations: 4-slot KV ring, ONE __syncthreads per
// 128 keys. Ring audit: staged pair was read before the last sync (WAR ok);
// computed pair was staged before the last sync, which drains vmcnt (RAW ok).
// Row-sum on VALU (lane-local over qrow=l31) + shfl reduce once at epilogue.
// swz2 on Q/K/V tiles breaks the 32x32 pattern's 4-way bank collisions.
__global__ __launch_bounds__(256, 2) void attn_kernel(
        const u16* __restrict__ qh, const u16* __restrict__ kh,
        const u16* __restrict__ Vt, u16* __restrict__ ao) {
    __shared__ __align__(16) u16 Qs[8192];       // 16KB  [128 q][64 dk]
    __shared__ __align__(16) u16 Ks[4][4096];    // 32KB ring [64 key][64 dk]
    __shared__ __align__(16) u16 Vs[4][4096];    // 32KB ring [64 dk][64 key]

    const int tid = threadIdx.x, lane = tid & 63, w = tid >> 6;
    const int l31 = lane & 31, hh = lane >> 5;
    const int lg = xcd_swz(blockIdx.x, 64);      // 512 = 8 * 64
    const int bh = lg >> 4, qt = lg & 15;
    const u16* qg = qh + ((size_t)bh * S_ + qt * 128) * DK_;
    const u16* kg = kh + (size_t)bh * S_ * DK_;
    const u16* vg = Vt + (size_t)bh * DK_ * S_;

    auto stageKV = [&](int slot, int kt) {
#pragma unroll
        for (int r = 0; r < 2; ++r) {
            int s = tid + (r << 8);
            int lin = swz2(s);                   // involution: pre-swizzled src
            int row = lin >> 3, ch = lin & 7;
            GLOAD16(kg + (size_t)(kt * 64 + row) * 64 + (ch << 3),
                    (char*)(&Ks[slot][0]) + ((r << 8) + (w << 6)) * 16);
            GLOAD16(vg + (size_t)row * S_ + kt * 64 + (ch << 3),
                    (char*)(&Vs[slot][0]) + ((r << 8) + (w << 6)) * 16);
        }
    };

    // prologue: stage Q tile + KV tiles 0,1
#pragma unroll
    for (int r = 0; r < 4; ++r) {
        int s = tid + (r << 8);
        int lin = swz2(s);
        int row = lin >> 3, ch = lin & 7;
        GLOAD16(qg + row * 64 + (ch << 3), (char*)Qs + ((r << 8) + (w << 6)) * 16);
    }
    stageKV(0, 0);
    stageKV(1, 1);
    asm volatile("s_waitcnt vmcnt(0)" ::: "memory");
    __syncthreads();

    // Q fragments (B-operand, 32x32x16): col=qrow=l31, dk = c*16 + hh*8 ..+8
    bf16x8 qf[4];
#pragma unroll
    for (int c = 0; c < 4; ++c) {
        int row = w * 32 + l31;
        qf[c] = *(const bf16x8*)((const char*)Qs + swz2(row * 8 + c * 2 + hh) * 16);
    }

    f32x16 acc[2] = {};      // PV out: col=dk(l31)+nb*32, row=q reg-layout
    float rs = 0.f;          // lane-local row-sum (qrow=l31+w*32, my hh keys)

    // one 2-tile iteration body: QK -> exp2/pack (rs +=) -> PV
#define ATTN_TILE(SLOT, PAOUT)                                                   \
    {                                                                            \
        const char* Kb = (const char*)&Ks[SLOT][0];                              \
        f32x16 st[2] = {};                                                       \
        _Pragma("unroll") for (int kb = 0; kb < 2; ++kb) {                       \
            bf16x8 kf[4];                                                        \
            _Pragma("unroll") for (int c = 0; c < 4; ++c) {                      \
                int row = kb * 32 + l31;                                         \
                kf[c] = *(const bf16x8*)(Kb + swz2(row * 8 + c * 2 + hh) * 16);  \
            }                                                                    \
            __builtin_amdgcn_s_setprio(1);                                       \
            _Pragma("unroll") for (int c = 0; c < 4; ++c)                        \
                st[kb] = __builtin_amdgcn_mfma_f32_32x32x16_bf16(                \
                    kf[c], qf[c], st[kb], 0, 0, 0);                              \
            __builtin_amdgcn_s_setprio(0);                                       \
        }                                                                        \
        _Pragma("unroll") for (int c = 0; c < 4; ++c) {                          \
            const int kb = c >> 1, o = (c & 1) * 8;                              \
            float e0 = exp2f_fast(st[kb][o + 0]);                                \
            float e1 = exp2f_fast(st[kb][o + 1]);                                \
            float e2 = exp2f_fast(st[kb][o + 2]);                                \
            float e3 = exp2f_fast(st[kb][o + 3]);                                \
            float e4 = exp2f_fast(st[kb][o + 4]);                                \
            float e5 = exp2f_fast(st[kb][o + 5]);                                \
            float e6 = exp2f_fast(st[kb][o + 6]);                                \
            float e7 = exp2f_fast(st[kb][o + 7]);                                \
            rs += ((e0 + e1) + (e2 + e3)) + ((e4 + e5) + (e6 + e7));             \
            uint32_t u0 = cvtpk_bf16(e0, e1);                                    \
            uint32_t u1 = cvtpk_bf16(e2, e3);                                    \
            uint32_t u2 = cvtpk_bf16(e4, e5);                                    \
            uint32_t u3 = cvtpk_bf16(e6, e7);                                    \
            asm volatile("v_permlane32_swap_b32 %0, %1" : "+v"(u0), "+v"(u2));   \
            asm volatile("v_permlane32_swap_b32 %0, %1" : "+v"(u1), "+v"(u3));   \
            union { uint32_t u[4]; bf16x8 v; } pu;                               \
            pu.u[0] = u0; pu.u[1] = u1; pu.u[2] = u2; pu.u[3] = u3;              \
            PAOUT[c] = pu.v;                                                     \
        }                                                                        \
        const char* Vb = (const char*)&Vs[SLOT][0];                              \
        _Pragma("unroll") for (int nb = 0; nb < 2; ++nb) {                       \
            bf16x8 vf[4];                                                        \
            _Pragma("unroll") for (int c = 0; c < 4; ++c) {                      \
                int row = nb * 32 + l31;                                         \
                vf[c] = *(const bf16x8*)(Vb + swz2(row * 8 + c * 2 + hh) * 16);  \
            }                                                                    \
            __builtin_amdgcn_s_setprio(1);                                       \
            _Pragma("unroll") for (int c = 0; c < 4; ++c)                        \
                acc[nb] = __builtin_amdgcn_mfma_f32_32x32x16_bf16(               \
                    PAOUT[c], vf[c], acc[nb], 0, 0, 0);                          \
            __builtin_amdgcn_s_setprio(0);                                       \
        }                                                                        \
    }

#pragma unroll 1
    for (int i = 0; i < 16; ++i) {
        const int t = 2 * i;
        if (i < 15) {                            // stage next pair into the
            stageKV((t + 2) & 3, t + 2);         // slots read last iteration
            stageKV((t + 3) & 3, t + 3);         // (WAR guarded by last sync)
        }
        bf16x8 pa0[4], pa1[4];
        ATTN_TILE((t) & 3, pa0);
        ATTN_TILE((t + 1) & 3, pa1);
        __syncthreads();   // drains vmcnt (stage landed) + guards ring reuse
    }
#undef ATTN_TILE

    // epilogue: combine the two hh-halves' row-sums, divide, store bf16
    rs += __shfl_xor(rs, 32);                    // total row-sum for qrow=l31
    const int bb = bh >> 4, hd = bh & 15;
#pragma unroll
    for (int r = 0; r < 16; ++r) {
        int ql = (r & 3) + 8 * (r >> 2) + 4 * hh;
        float inv = 1.0f / __shfl(rs, ql);       // rs for qrow=ql lives at lane ql
        int srow = qt * 128 + w * 32 + ql;
#pragma unroll
        for (int nb = 0; nb < 2; ++nb) {
            int col = hd * 64 + nb * 32 + l31;
            ao[((size_t)bb * S_ + srow) * D_ + col] = f2bf(acc[nb][r] * inv);
        }
    }
}

// ---------------------------------------------------------------- launch
extern "C" void kernel_launch(void* const* d_in, const int* in_sizes, int n_in,
                              void* d_out, int out_size, void* d_ws, size_t ws_size,
                              hipStream_t stream) {
    const float* q  = (const float*)d_in[0];
    const float* k  = (const float*)d_in[1];
    const float* v  = (const float*)d_in[2];
    const float* Wq = (const float*)d_in[3];
    const float* bq = (const float*)d_in[4];
    const float* Wk = (const float*)d_in[5];
    const float* bk = (const float*)d_in[6];
    const float* Wv = (const float*)d_in[7];
    const float* bv = (const float*)d_in[8];
    const float* Wo = (const float*)d_in[9];
    const float* bo = (const float*)d_in[10];

    char* ws = (char*)d_ws;
    u16* qb  = (u16*)(ws);                  // 8 MiB
    u16* kb  = (u16*)(ws + (8u  << 20));    // 8 MiB (reused as attn-out)
    u16* vb  = (u16*)(ws + (16u << 20));    // 8 MiB
    u16* Wqb = (u16*)(ws + (24u << 20));    // 2 MiB each
    u16* Wkb = (u16*)(ws + (26u << 20));
    u16* Wvb = (u16*)(ws + (28u << 20));
    u16* Wob = (u16*)(ws + (30u << 20));
    u16* qhb = (u16*)(ws + (32u << 20));    // 8 MiB [B,H,S,DK]
    u16* khb = (u16*)(ws + (40u << 20));    // 8 MiB [B,H,S,DK]
    u16* Vtb = (u16*)(ws + (48u << 20));    // 8 MiB [BH,DK,S]
    u16* aob = kb;                          // alias: kb dead after qkv

    cast_all_kernel<<<8192, 256, 0, stream>>>(q, k, v, Wq, Wk, Wv, Wo,
                                              qb, kb, vb, Wqb, Wkb, Wvb, Wob);

    qkv256_kernel<<<192, 512, 0, stream>>>(
        qb, kb, vb, Wqb, Wkb, Wvb, bq, bk, bv, qhb, khb, Vtb);

    attn_kernel<<<512, 256, 0, stream>>>(qhb, khb, Vtb, aob);

    oproj_kernel<<<256, 256, 0, stream>>>(aob, Wob, bo, (float*)d_out);
}